// Round 5
// baseline (483.951 us; speedup 1.0000x reference)
//
#include <hip/hip_runtime.h>
#include <stdint.h>

#define DIM 256
#define NEMB 8192
#define NTOK 16384
#define HW 1024

typedef __attribute__((ext_vector_type(4))) int int4v;

// ---- helpers ----
__device__ __forceinline__ void async_cp16(void* lds, const void* g) {
  __builtin_amdgcn_global_load_lds(
      (const __attribute__((address_space(1))) unsigned int*)g,
      (__attribute__((address_space(3))) unsigned int*)lds, 16, 0, 0);
}
// x ~ s*(q0 + q1/128), s = 1/20
__device__ __forceinline__ int q0_of(float x) {
  int q = __float2int_rn(x * 20.0f);
  return q > 127 ? 127 : (q < -127 ? -127 : q);
}
__device__ __forceinline__ int q1_of(float x, int q0) {
  float e = x * 20.0f - (float)q0;
  int q = __float2int_rn(e * 128.0f);
  return q > 127 ? 127 : (q < -127 ? -127 : q);
}
__device__ __forceinline__ unsigned int pack4(int a, int b, int c, int d) {
  return (unsigned int)(a & 0xff) | ((unsigned int)(b & 0xff) << 8) |
         ((unsigned int)(c & 0xff) << 16) | ((unsigned int)(d & 0xff) << 24);
}

// ---- kernel 1: quantize emb table to int8 q0/q1 + scaled int row sumsq ----
// iwsq2 = rint(wsq*25600) + 8192  (SC units = 1/25600, +bias)
__global__ __launch_bounds__(256) void prep_w_kernel(
    const float* __restrict__ emb, unsigned int* __restrict__ q0w,
    unsigned int* __restrict__ q1w, int* __restrict__ iwsq2) {
  int lane = threadIdx.x & 63;
  int row = blockIdx.x * 4 + (threadIdx.x >> 6);
  const float4 v = *(const float4*)(emb + (size_t)row * DIM + lane * 4);
  float s = v.x * v.x + v.y * v.y + v.z * v.z + v.w * v.w;
  int a0 = q0_of(v.x), b0 = q0_of(v.y), c0 = q0_of(v.z), d0 = q0_of(v.w);
  q0w[row * (DIM / 4) + lane] = pack4(a0, b0, c0, d0);
  q1w[row * (DIM / 4) + lane] =
      pack4(q1_of(v.x, a0), q1_of(v.y, b0), q1_of(v.z, c0), q1_of(v.w, d0));
#pragma unroll
  for (int off = 32; off > 0; off >>= 1) s += __shfl_xor(s, off, 64);
  if (lane == 0) iwsq2[row] = (int)rintf(s * 25600.0f) + 8192;
}

// ---- kernel 2: transpose z -> token-major int8 q0/q1 + token-major fp32 ----
__global__ __launch_bounds__(256) void prep_z_kernel(
    const float* __restrict__ z, unsigned int* __restrict__ q0z,
    unsigned int* __restrict__ q1z, float* __restrict__ zf32) {
  __shared__ float tile[64][65];
  int b = blockIdx.x, d0 = blockIdx.y * 64, hw0 = blockIdx.z * 64;
  int tid = threadIdx.x;
  int lane = tid & 63, grp = tid >> 6;
  const float* src = z + (size_t)b * DIM * HW + hw0 + lane;
#pragma unroll
  for (int i = 0; i < 16; i++) {
    int dl = grp + i * 4;
    tile[dl][lane] = src[(size_t)(d0 + dl) * HW];  // coalesced along hw
  }
  __syncthreads();
  int dq = tid & 15;  // covers 4 d's
#pragma unroll
  for (int p = 0; p < 4; p++) {
    int n = (tid >> 4) + p * 16;  // hw_local
    float x0 = tile[dq * 4 + 0][n], x1 = tile[dq * 4 + 1][n];
    float x2 = tile[dq * 4 + 2][n], x3 = tile[dq * 4 + 3][n];
    int a0 = q0_of(x0), b0 = q0_of(x1), c0 = q0_of(x2), e0 = q0_of(x3);
    int token = b * HW + hw0 + n;
    size_t off = (size_t)token * (DIM / 4) + (d0 >> 2) + dq;
    q0z[off] = pack4(a0, b0, c0, e0);
    q1z[off] = pack4(q1_of(x0, a0), q1_of(x1, b0), q1_of(x2, c0), q1_of(x3, e0));
    *(float4*)(zf32 + (size_t)token * DIM + d0 + dq * 4) =
        make_float4(x0, x1, x2, x3);
  }
}

// ---- kernel 3: k-inner GEMM + packed-u32 top-2 per (kq, wt) quadrant ----
// block = 128 tokens x one 2048-code quarter; 32 iters of 64-code tiles.
// acc = 128*q0z.q0w + q0z.q1w + q1z.q0w ; score_int = iwsq2 - acc
// pack = ((clamp(score)>>6)<<13) | idx13
__global__ __launch_bounds__(512, 4) void gemm_topk_kernel(
    const signed char* __restrict__ q0z, const signed char* __restrict__ q1z,
    const signed char* __restrict__ q0w, const signed char* __restrict__ q1w,
    const int* __restrict__ iwsq2, uint2* __restrict__ partials) {
  // [buf][arr: 0=q0w k0-127, 1=q0w k128-255, 2=q1w k0-127, 3=q1w k128-255]
  // 64 rows x 128 B per array; chunk t in row holds global chunk t^(row&7)
  __shared__ __align__(16) signed char sB[2][4][64 * 128];

  const int tg = blockIdx.x;  // 0..127 token group
  const int kq = blockIdx.y;  // 0..3 code quarter
  const int tid = threadIdx.x;
  const int lane = tid & 63, w = tid >> 6;
  const int wm = w >> 1, wt = w & 1;  // 4 token-rows x 2 code-cols of waves
  const int c = lane & 15, quad = lane >> 4;
  const int n0 = tg * 128;
  const int k0g = kq * 2048;

  // A fragments: global -> registers, once. A[m=lane&15][chunk=s*4+quad]
  int4v af0[2][4], af1[2][4];
#pragma unroll
  for (int tm = 0; tm < 2; tm++) {
    const size_t row = (size_t)(n0 + wm * 32 + tm * 16 + c) * DIM;
#pragma unroll
    for (int s = 0; s < 4; s++) {
      af0[tm][s] = *(const int4v*)(q0z + row + s * 64 + quad * 16);
      af1[tm][s] = *(const int4v*)(q1z + row + s * 64 + quad * 16);
    }
  }

  // stage tile for iter 0
  {
    const int row = tid >> 3, t = tid & 7;
    const int cl = (t ^ (row & 7)) * 16;
    const size_t rb = (size_t)(k0g + row) * DIM;
    async_cp16(&sB[0][0][tid * 16], q0w + rb + cl);
    async_cp16(&sB[0][1][tid * 16], q0w + rb + 128 + cl);
    async_cp16(&sB[0][2][tid * 16], q1w + rb + cl);
    async_cp16(&sB[0][3][tid * 16], q1w + rb + 128 + cl);
  }
  __syncthreads();

  unsigned int m1[8], m2[8];
#pragma unroll
  for (int i = 0; i < 8; i++) { m1[i] = 0xFFFFFFFFu; m2[i] = 0xFFFFFFFFu; }

  unsigned int idxA = (unsigned)(k0g + wt * 32 + c);
  unsigned int idxB = idxA + 16;
  const int4v zero = {0, 0, 0, 0};

#pragma unroll 2
  for (int it = 0; it < 32; it++) {
    const int buf = it & 1;
    // stage next tile into the other buffer (last iter: dup re-stage, unread)
    {
      const int itn = (it + 1 < 32) ? it + 1 : 31;
      const int nb = buf ^ 1;
      const int row = tid >> 3, t = tid & 7;
      const int cl = (t ^ (row & 7)) * 16;
      const size_t rb = (size_t)(k0g + itn * 64 + row) * DIM;
      async_cp16(&sB[nb][0][tid * 16], q0w + rb + cl);
      async_cp16(&sB[nb][1][tid * 16], q0w + rb + 128 + cl);
      async_cp16(&sB[nb][2][tid * 16], q1w + rb + cl);
      async_cp16(&sB[nb][3][tid * 16], q1w + rb + 128 + cl);
    }
    // per-iter row sumsq (L1-hot)
    const int iw0 = iwsq2[k0g + it * 64 + wt * 32 + c];
    const int iw1 = iwsq2[k0g + it * 64 + wt * 32 + 16 + c];
    // B fragments from LDS: chunk g = s*4+quad; half = s>>1; t = (g&7)^(row&7)
    int4v b0[2][4], b1[2][4];
#pragma unroll
    for (int tn = 0; tn < 2; tn++) {
      const int row = wt * 32 + tn * 16 + c;
#pragma unroll
      for (int s = 0; s < 4; s++) {
        const int half = s >> 1;
        const int t = (((s & 1) * 4 + quad) ^ (c & 7)) * 16;  // row&7 == c&7
        b0[tn][s] = *(const int4v*)(&sB[buf][half][row * 128 + t]);
        b1[tn][s] = *(const int4v*)(&sB[buf][2 + half][row * 128 + t]);
      }
    }
    int4v acc[2][2];
#pragma unroll
    for (int tm = 0; tm < 2; tm++) {
#pragma unroll
      for (int tn = 0; tn < 2; tn++) {
        int4v a = __builtin_amdgcn_mfma_i32_16x16x64_i8(af0[tm][0], b0[tn][0],
                                                        zero, 0, 0, 0);
#pragma unroll
        for (int s = 1; s < 4; s++)
          a = __builtin_amdgcn_mfma_i32_16x16x64_i8(af0[tm][s], b0[tn][s], a,
                                                    0, 0, 0);
#pragma unroll
        for (int r = 0; r < 4; r++) a[r] <<= 7;  // 128*P00
#pragma unroll
        for (int s = 0; s < 4; s++)
          a = __builtin_amdgcn_mfma_i32_16x16x64_i8(af0[tm][s], b1[tn][s], a,
                                                    0, 0, 0);
#pragma unroll
        for (int s = 0; s < 4; s++)
          a = __builtin_amdgcn_mfma_i32_16x16x64_i8(af1[tm][s], b0[tn][s], a,
                                                    0, 0, 0);
        acc[tm][tn] = a;
      }
    }
    // epilogue: packed-u32 top-2 insert (C/D: col=lane&15, row=quad*4+r)
#pragma unroll
    for (int tm = 0; tm < 2; tm++) {
#pragma unroll
      for (int r = 0; r < 4; r++) {
        unsigned int s0 = (unsigned int)(iw0 - acc[tm][0][r]);
        unsigned int s1 = (unsigned int)(iw1 - acc[tm][1][r]);
        s0 = s0 < 0x2000000u ? s0 : 0x1FFFFFFu;
        s1 = s1 < 0x2000000u ? s1 : 0x1FFFFFFu;
        unsigned int p0 = ((s0 << 7) & 0xFFFFE000u) | idxA;
        unsigned int p1 = ((s1 << 7) & 0xFFFFE000u) | idxB;
        unsigned int v = p0 < p1 ? p0 : p1;
        const int ix = tm * 4 + r;
        unsigned int lo = v < m1[ix] ? v : m1[ix];
        unsigned int hi = v < m1[ix] ? m1[ix] : v;
        m2[ix] = m2[ix] < hi ? m2[ix] : hi;
        m1[ix] = lo;
      }
    }
    idxA += 64;
    idxB += 64;
    __syncthreads();  // drains next-tile staging (in flight all compute phase)
  }

  // merge top-2 across the 16 c-lanes (idx rides in low bits)
#pragma unroll
  for (int ix = 0; ix < 8; ix++) {
    unsigned int a1 = m1[ix], a2 = m2[ix];
#pragma unroll
    for (int off = 1; off < 16; off <<= 1) {
      unsigned int o1 = __shfl_xor(a1, off, 16);
      unsigned int o2 = __shfl_xor(a2, off, 16);
      unsigned int n1 = a1 < o1 ? a1 : o1;
      unsigned int hi = a1 < o1 ? o1 : a1;
      unsigned int l2 = a2 < o2 ? a2 : o2;
      a2 = hi < l2 ? hi : l2;
      a1 = n1;
    }
    m1[ix] = a1;
    m2[ix] = a2;
  }
  if (c == 0) {
#pragma unroll
    for (int tm = 0; tm < 2; tm++) {
#pragma unroll
      for (int r = 0; r < 4; r++) {
        int token = tg * 128 + wm * 32 + tm * 16 + quad * 4 + r;
        partials[(size_t)(kq * 2 + wt) * NTOK + token] =
            make_uint2(m1[tm * 4 + r], m2[tm * 4 + r]);
      }
    }
  }
}

// ---- kernel 4: dedup + exact fp64 rescore of up to 16 candidates ----
__global__ __launch_bounds__(256) void rescore_kernel(
    const uint2* __restrict__ partials, const float* __restrict__ zf32,
    const float* __restrict__ emb, int* __restrict__ ids) {
  int w = threadIdx.x >> 6, lane = threadIdx.x & 63;
  int token = blockIdx.x * 4 + w;
  int cd[16];
#pragma unroll
  for (int q = 0; q < 8; q++) {
    uint2 p = partials[(size_t)q * NTOK + token];
    cd[q * 2] = (int)(p.x & 0x1FFFu);
    cd[q * 2 + 1] = (int)(p.y & 0x1FFFu);
  }
  const float4 zv = *(const float4*)(zf32 + (size_t)token * DIM + lane * 4);
  double best = 1e300;
  int bid = NEMB;
#pragma unroll
  for (int q = 0; q < 16; q++) {
    bool dup = false;
#pragma unroll
    for (int j = 0; j < 16; j++)
      if (j < q) dup = dup || (cd[j] == cd[q]);
    if (!dup) {  // wave-uniform branch
      const float4 wv = *(const float4*)(emb + (size_t)cd[q] * DIM + lane * 4);
      double s = (double)wv.x * ((double)wv.x - 2.0 * (double)zv.x) +
                 (double)wv.y * ((double)wv.y - 2.0 * (double)zv.y) +
                 (double)wv.z * ((double)wv.z - 2.0 * (double)zv.z) +
                 (double)wv.w * ((double)wv.w - 2.0 * (double)zv.w);
#pragma unroll
      for (int off = 32; off > 0; off >>= 1) s += __shfl_xor(s, off, 64);
      if (s < best || (s == best && cd[q] < bid)) {
        best = s;
        bid = cd[q];
      }
    }
  }
  if (lane == 0) ids[token] = bid;
}

// ---- kernel 5: gather emb rows, transpose to [B,D,H,W] via LDS ----
__global__ __launch_bounds__(256) void gather_kernel(
    const int* __restrict__ ids, const float* __restrict__ emb,
    float* __restrict__ out) {
  __shared__ float tile[32][257];
  __shared__ int sid[32];
  int b = blockIdx.x;
  int hw0 = blockIdx.y * 32;
  int tid = threadIdx.x;
  if (tid < 32) sid[tid] = ids[b * HW + hw0 + tid];
  __syncthreads();
  for (int i = 0; i < 32; i++)
    tile[i][tid] = emb[(size_t)sid[i] * DIM + tid];  // coalesced 1KB row loads
  __syncthreads();
  int h = tid & 31, dg = tid >> 5;
  for (int i = 0; i < 32; i++) {
    int d = i * 8 + dg;
    out[(size_t)b * DIM * HW + (size_t)d * HW + hw0 + h] = tile[h][d];
  }
}

extern "C" void kernel_launch(void* const* d_in, const int* in_sizes, int n_in,
                              void* d_out, int out_size, void* d_ws, size_t ws_size,
                              hipStream_t stream) {
  const float* z = (const float*)d_in[0];    // [16,256,32,32]
  const float* emb = (const float*)d_in[1];  // [8192,256]
  float* out = (float*)d_out;
  char* ws = (char*)d_ws;

  // zf32 (16 MB) lives in d_out — dead until gather overwrites it.
  float* zf32 = (float*)d_out;

  // ws: q0w 2M | q1w 2M | q0z 4M | q1z 4M | iwsq2 32K | partials 1M | ids 64K
  signed char* q0w = (signed char*)(ws);
  signed char* q1w = (signed char*)(ws + 2097152);
  signed char* q0z = (signed char*)(ws + 4194304);
  signed char* q1z = (signed char*)(ws + 8388608);
  int* iwsq2 = (int*)(ws + 12582912);
  uint2* partials = (uint2*)(ws + 12615680);
  int* ids = (int*)(ws + 13664256);

  prep_w_kernel<<<dim3(2048), 256, 0, stream>>>(emb, (unsigned int*)q0w,
                                                (unsigned int*)q1w, iwsq2);
  prep_z_kernel<<<dim3(16, 4, 16), 256, 0, stream>>>(z, (unsigned int*)q0z,
                                                     (unsigned int*)q1z, zf32);
  gemm_topk_kernel<<<dim3(128, 4), 512, 0, stream>>>(q0z, q1z, q0w, q1w, iwsq2,
                                                     partials);
  rescore_kernel<<<dim3(4096), 256, 0, stream>>>(partials, zf32, emb, ids);
  gather_kernel<<<dim3(16, 32), 256, 0, stream>>>(ids, emb, out);
}

// Round 6
// 216.250 us; speedup vs baseline: 2.2379x; 2.2379x over previous
//
#include <hip/hip_runtime.h>
#include <stdint.h>

#define DIM 256
#define NEMB 8192
#define NTOK 16384
#define HW 1024

typedef __attribute__((ext_vector_type(4))) int int4v;

// ---- helpers ----
__device__ __forceinline__ void async_cp16(void* lds, const void* g) {
  __builtin_amdgcn_global_load_lds(
      (const __attribute__((address_space(1))) unsigned int*)g,
      (__attribute__((address_space(3))) unsigned int*)lds, 16, 0, 0);
}
// x ~ s*(q0 + q1/128), s = 1/20
__device__ __forceinline__ int q0_of(float x) {
  int q = __float2int_rn(x * 20.0f);
  return q > 127 ? 127 : (q < -127 ? -127 : q);
}
__device__ __forceinline__ int q1_of(float x, int q0) {
  float e = x * 20.0f - (float)q0;
  int q = __float2int_rn(e * 128.0f);
  return q > 127 ? 127 : (q < -127 ? -127 : q);
}
__device__ __forceinline__ unsigned int pack4(int a, int b, int c, int d) {
  return (unsigned int)(a & 0xff) | ((unsigned int)(b & 0xff) << 8) |
         ((unsigned int)(c & 0xff) << 16) | ((unsigned int)(d & 0xff) << 24);
}

// ---- kernel 1: quantize emb table to int8 q0/q1 + scaled int row sumsq ----
// iwsq2 = rint(wsq*25600) + 8192  (SC units = 1/25600, +bias)
__global__ __launch_bounds__(256) void prep_w_kernel(
    const float* __restrict__ emb, unsigned int* __restrict__ q0w,
    unsigned int* __restrict__ q1w, int* __restrict__ iwsq2) {
  int lane = threadIdx.x & 63;
  int row = blockIdx.x * 4 + (threadIdx.x >> 6);
  const float4 v = *(const float4*)(emb + (size_t)row * DIM + lane * 4);
  float s = v.x * v.x + v.y * v.y + v.z * v.z + v.w * v.w;
  int a0 = q0_of(v.x), b0 = q0_of(v.y), c0 = q0_of(v.z), d0 = q0_of(v.w);
  q0w[row * (DIM / 4) + lane] = pack4(a0, b0, c0, d0);
  q1w[row * (DIM / 4) + lane] =
      pack4(q1_of(v.x, a0), q1_of(v.y, b0), q1_of(v.z, c0), q1_of(v.w, d0));
#pragma unroll
  for (int off = 32; off > 0; off >>= 1) s += __shfl_xor(s, off, 64);
  if (lane == 0) iwsq2[row] = (int)rintf(s * 25600.0f) + 8192;
}

// ---- kernel 2: transpose z -> token-major int8 q0/q1 + token-major fp32 ----
__global__ __launch_bounds__(256) void prep_z_kernel(
    const float* __restrict__ z, unsigned int* __restrict__ q0z,
    unsigned int* __restrict__ q1z, float* __restrict__ zf32) {
  __shared__ float tile[64][65];
  int b = blockIdx.x, d0 = blockIdx.y * 64, hw0 = blockIdx.z * 64;
  int tid = threadIdx.x;
  int lane = tid & 63, grp = tid >> 6;
  const float* src = z + (size_t)b * DIM * HW + hw0 + lane;
#pragma unroll
  for (int i = 0; i < 16; i++) {
    int dl = grp + i * 4;
    tile[dl][lane] = src[(size_t)(d0 + dl) * HW];  // coalesced along hw
  }
  __syncthreads();
  int dq = tid & 15;  // covers 4 d's
#pragma unroll
  for (int p = 0; p < 4; p++) {
    int n = (tid >> 4) + p * 16;  // hw_local
    float x0 = tile[dq * 4 + 0][n], x1 = tile[dq * 4 + 1][n];
    float x2 = tile[dq * 4 + 2][n], x3 = tile[dq * 4 + 3][n];
    int a0 = q0_of(x0), b0 = q0_of(x1), c0 = q0_of(x2), e0 = q0_of(x3);
    int token = b * HW + hw0 + n;
    size_t off = (size_t)token * (DIM / 4) + (d0 >> 2) + dq;
    q0z[off] = pack4(a0, b0, c0, e0);
    q1z[off] = pack4(q1_of(x0, a0), q1_of(x1, b0), q1_of(x2, c0), q1_of(x3, e0));
    *(float4*)(zf32 + (size_t)token * DIM + d0 + dq * 4) =
        make_float4(x0, x1, x2, x3);
  }
}

// ---- kernel 3: k-inner GEMM + packed-u32 top-2 per (kq, wt) quadrant ----
// block = 128 tokens x one 2048-code quarter; 32 iters of 64-code tiles.
// acc = 128*q0z.q0w + q0z.q1w + q1z.q0w ; score_int = iwsq2 - acc
// pack = ((clamp(score)>>6)<<13) | idx13
// launch_bounds MUST stay (512,2): (512,4) caps VGPR at 128 -> scratch spill
// (round 5: WRITE_SIZE 0.5->393 MB, FETCH 20->1068 MB, 3.2x slower).
__global__ __launch_bounds__(512, 2) void gemm_topk_kernel(
    const signed char* __restrict__ q0z, const signed char* __restrict__ q1z,
    const signed char* __restrict__ q0w, const signed char* __restrict__ q1w,
    const int* __restrict__ iwsq2, uint2* __restrict__ partials) {
  // [buf][arr: 0=q0w k0-127, 1=q0w k128-255, 2=q1w k0-127, 3=q1w k128-255]
  // 64 rows x 128 B per array; chunk t in row holds global chunk t^(row&7)
  __shared__ __align__(16) signed char sB[2][4][64 * 128];

  // XCD-aware mapping: 8 XCDs round-robin on bid; pin each code-quarter kq
  // to one XCD pair so per-XCD L2 holds 1 MB of B instead of 4 MB.
  const int bid = blockIdx.x;           // 0..511
  const int xcd = bid & 7;
  const int kq = xcd >> 1;              // 0..3 code quarter
  const int tg = (bid >> 3) + ((xcd & 1) << 6);  // 0..127 token group
  const int tid = threadIdx.x;
  const int lane = tid & 63, w = tid >> 6;
  const int wm = w >> 1, wt = w & 1;  // 4 token-rows x 2 code-cols of waves
  const int c = lane & 15, quad = lane >> 4;
  const int n0 = tg * 128;
  const int k0g = kq * 2048;

  // A fragments: global -> registers, once. A[m=lane&15][chunk=s*4+quad]
  int4v af0[2][4], af1[2][4];
#pragma unroll
  for (int tm = 0; tm < 2; tm++) {
    const size_t row = (size_t)(n0 + wm * 32 + tm * 16 + c) * DIM;
#pragma unroll
    for (int s = 0; s < 4; s++) {
      af0[tm][s] = *(const int4v*)(q0z + row + s * 64 + quad * 16);
      af1[tm][s] = *(const int4v*)(q1z + row + s * 64 + quad * 16);
    }
  }

  // stage tile for iter 0
  {
    const int row = tid >> 3, t = tid & 7;
    const int cl = (t ^ (row & 7)) * 16;
    const size_t rb = (size_t)(k0g + row) * DIM;
    async_cp16(&sB[0][0][tid * 16], q0w + rb + cl);
    async_cp16(&sB[0][1][tid * 16], q0w + rb + 128 + cl);
    async_cp16(&sB[0][2][tid * 16], q1w + rb + cl);
    async_cp16(&sB[0][3][tid * 16], q1w + rb + 128 + cl);
  }
  __syncthreads();

  unsigned int m1[8], m2[8];
#pragma unroll
  for (int i = 0; i < 8; i++) { m1[i] = 0xFFFFFFFFu; m2[i] = 0xFFFFFFFFu; }

  unsigned int idxA = (unsigned)(k0g + wt * 32 + c);
  unsigned int idxB = idxA + 16;
  const int4v zero = {0, 0, 0, 0};

#pragma unroll 2
  for (int it = 0; it < 32; it++) {
    const int buf = it & 1;
    // stage next tile into the other buffer (last iter: dup re-stage, unread)
    {
      const int itn = (it + 1 < 32) ? it + 1 : 31;
      const int nb = buf ^ 1;
      const int row = tid >> 3, t = tid & 7;
      const int cl = (t ^ (row & 7)) * 16;
      const size_t rb = (size_t)(k0g + itn * 64 + row) * DIM;
      async_cp16(&sB[nb][0][tid * 16], q0w + rb + cl);
      async_cp16(&sB[nb][1][tid * 16], q0w + rb + 128 + cl);
      async_cp16(&sB[nb][2][tid * 16], q1w + rb + cl);
      async_cp16(&sB[nb][3][tid * 16], q1w + rb + 128 + cl);
    }
    // per-iter row sumsq (L1-hot)
    const int iw0 = iwsq2[k0g + it * 64 + wt * 32 + c];
    const int iw1 = iwsq2[k0g + it * 64 + wt * 32 + 16 + c];
    // B fragments from LDS: chunk g = s*4+quad; half = s>>1; t = (g&7)^(row&7)
    int4v b0[2][4], b1[2][4];
#pragma unroll
    for (int tn = 0; tn < 2; tn++) {
      const int row = wt * 32 + tn * 16 + c;
#pragma unroll
      for (int s = 0; s < 4; s++) {
        const int half = s >> 1;
        const int t = (((s & 1) * 4 + quad) ^ (c & 7)) * 16;  // row&7 == c&7
        b0[tn][s] = *(const int4v*)(&sB[buf][half][row * 128 + t]);
        b1[tn][s] = *(const int4v*)(&sB[buf][2 + half][row * 128 + t]);
      }
    }
    int4v acc[2][2];
#pragma unroll
    for (int tm = 0; tm < 2; tm++) {
#pragma unroll
      for (int tn = 0; tn < 2; tn++) {
        int4v a = __builtin_amdgcn_mfma_i32_16x16x64_i8(af0[tm][0], b0[tn][0],
                                                        zero, 0, 0, 0);
#pragma unroll
        for (int s = 1; s < 4; s++)
          a = __builtin_amdgcn_mfma_i32_16x16x64_i8(af0[tm][s], b0[tn][s], a,
                                                    0, 0, 0);
#pragma unroll
        for (int r = 0; r < 4; r++) a[r] <<= 7;  // 128*P00
#pragma unroll
        for (int s = 0; s < 4; s++)
          a = __builtin_amdgcn_mfma_i32_16x16x64_i8(af0[tm][s], b1[tn][s], a,
                                                    0, 0, 0);
#pragma unroll
        for (int s = 0; s < 4; s++)
          a = __builtin_amdgcn_mfma_i32_16x16x64_i8(af1[tm][s], b0[tn][s], a,
                                                    0, 0, 0);
        acc[tm][tn] = a;
      }
    }
    // epilogue: packed-u32 top-2 insert (C/D: col=lane&15, row=quad*4+r)
#pragma unroll
    for (int tm = 0; tm < 2; tm++) {
#pragma unroll
      for (int r = 0; r < 4; r++) {
        unsigned int s0 = (unsigned int)(iw0 - acc[tm][0][r]);
        unsigned int s1 = (unsigned int)(iw1 - acc[tm][1][r]);
        s0 = s0 < 0x2000000u ? s0 : 0x1FFFFFFu;
        s1 = s1 < 0x2000000u ? s1 : 0x1FFFFFFu;
        unsigned int p0 = ((s0 << 7) & 0xFFFFE000u) | idxA;
        unsigned int p1 = ((s1 << 7) & 0xFFFFE000u) | idxB;
        unsigned int v = p0 < p1 ? p0 : p1;
        const int ix = tm * 4 + r;
        unsigned int lo = v < m1[ix] ? v : m1[ix];
        unsigned int hi = v < m1[ix] ? m1[ix] : v;
        m2[ix] = m2[ix] < hi ? m2[ix] : hi;
        m1[ix] = lo;
      }
    }
    idxA += 64;
    idxB += 64;
    __syncthreads();  // drains next-tile staging (in flight all compute phase)
  }

  // merge top-2 across the 16 c-lanes (idx rides in low bits)
#pragma unroll
  for (int ix = 0; ix < 8; ix++) {
    unsigned int a1 = m1[ix], a2 = m2[ix];
#pragma unroll
    for (int off = 1; off < 16; off <<= 1) {
      unsigned int o1 = __shfl_xor(a1, off, 16);
      unsigned int o2 = __shfl_xor(a2, off, 16);
      unsigned int n1 = a1 < o1 ? a1 : o1;
      unsigned int hi = a1 < o1 ? o1 : a1;
      unsigned int l2 = a2 < o2 ? a2 : o2;
      a2 = hi < l2 ? hi : l2;
      a1 = n1;
    }
    m1[ix] = a1;
    m2[ix] = a2;
  }
  if (c == 0) {
#pragma unroll
    for (int tm = 0; tm < 2; tm++) {
#pragma unroll
      for (int r = 0; r < 4; r++) {
        int token = tg * 128 + wm * 32 + tm * 16 + quad * 4 + r;
        partials[(size_t)(kq * 2 + wt) * NTOK + token] =
            make_uint2(m1[tm * 4 + r], m2[tm * 4 + r]);
      }
    }
  }
}

// ---- kernel 4: dedup + exact fp64 rescore of up to 16 candidates ----
__global__ __launch_bounds__(256) void rescore_kernel(
    const uint2* __restrict__ partials, const float* __restrict__ zf32,
    const float* __restrict__ emb, int* __restrict__ ids) {
  int w = threadIdx.x >> 6, lane = threadIdx.x & 63;
  int token = blockIdx.x * 4 + w;
  int cd[16];
#pragma unroll
  for (int q = 0; q < 8; q++) {
    uint2 p = partials[(size_t)q * NTOK + token];
    cd[q * 2] = (int)(p.x & 0x1FFFu);
    cd[q * 2 + 1] = (int)(p.y & 0x1FFFu);
  }
  const float4 zv = *(const float4*)(zf32 + (size_t)token * DIM + lane * 4);
  double best = 1e300;
  int bid = NEMB;
#pragma unroll
  for (int q = 0; q < 16; q++) {
    bool dup = false;
#pragma unroll
    for (int j = 0; j < 16; j++)
      if (j < q) dup = dup || (cd[j] == cd[q]);
    if (!dup) {  // wave-uniform branch
      const float4 wv = *(const float4*)(emb + (size_t)cd[q] * DIM + lane * 4);
      double s = (double)wv.x * ((double)wv.x - 2.0 * (double)zv.x) +
                 (double)wv.y * ((double)wv.y - 2.0 * (double)zv.y) +
                 (double)wv.z * ((double)wv.z - 2.0 * (double)zv.z) +
                 (double)wv.w * ((double)wv.w - 2.0 * (double)zv.w);
#pragma unroll
      for (int off = 32; off > 0; off >>= 1) s += __shfl_xor(s, off, 64);
      if (s < best || (s == best && cd[q] < bid)) {
        best = s;
        bid = cd[q];
      }
    }
  }
  if (lane == 0) ids[token] = bid;
}

// ---- kernel 5: gather emb rows, transpose to [B,D,H,W] via LDS ----
__global__ __launch_bounds__(256) void gather_kernel(
    const int* __restrict__ ids, const float* __restrict__ emb,
    float* __restrict__ out) {
  __shared__ float tile[32][257];
  __shared__ int sid[32];
  int b = blockIdx.x;
  int hw0 = blockIdx.y * 32;
  int tid = threadIdx.x;
  if (tid < 32) sid[tid] = ids[b * HW + hw0 + tid];
  __syncthreads();
  for (int i = 0; i < 32; i++)
    tile[i][tid] = emb[(size_t)sid[i] * DIM + tid];  // coalesced 1KB row loads
  __syncthreads();
  int h = tid & 31, dg = tid >> 5;
  for (int i = 0; i < 32; i++) {
    int d = i * 8 + dg;
    out[(size_t)b * DIM * HW + (size_t)d * HW + hw0 + h] = tile[h][d];
  }
}

extern "C" void kernel_launch(void* const* d_in, const int* in_sizes, int n_in,
                              void* d_out, int out_size, void* d_ws, size_t ws_size,
                              hipStream_t stream) {
  const float* z = (const float*)d_in[0];    // [16,256,32,32]
  const float* emb = (const float*)d_in[1];  // [8192,256]
  float* out = (float*)d_out;
  char* ws = (char*)d_ws;

  // zf32 (16 MB) lives in d_out — dead until gather overwrites it.
  float* zf32 = (float*)d_out;

  // ws: q0w 2M | q1w 2M | q0z 4M | q1z 4M | iwsq2 32K | partials 1M | ids 64K
  signed char* q0w = (signed char*)(ws);
  signed char* q1w = (signed char*)(ws + 2097152);
  signed char* q0z = (signed char*)(ws + 4194304);
  signed char* q1z = (signed char*)(ws + 8388608);
  int* iwsq2 = (int*)(ws + 12582912);
  uint2* partials = (uint2*)(ws + 12615680);
  int* ids = (int*)(ws + 13664256);

  prep_w_kernel<<<dim3(2048), 256, 0, stream>>>(emb, (unsigned int*)q0w,
                                                (unsigned int*)q1w, iwsq2);
  prep_z_kernel<<<dim3(16, 4, 16), 256, 0, stream>>>(z, (unsigned int*)q0z,
                                                     (unsigned int*)q1z, zf32);
  gemm_topk_kernel<<<dim3(512), 512, 0, stream>>>(q0z, q1z, q0w, q1w, iwsq2,
                                                  partials);
  rescore_kernel<<<dim3(4096), 256, 0, stream>>>(partials, zf32, emb, ids);
  gather_kernel<<<dim3(16, 32), 256, 0, stream>>>(ids, emb, out);
}

// Round 7
// 191.522 us; speedup vs baseline: 2.5269x; 1.1291x over previous
//
#include <hip/hip_runtime.h>
#include <stdint.h>

#define DIM 256
#define NEMB 8192
#define NTOK 16384
#define HW 1024

typedef __attribute__((ext_vector_type(4))) int int4v;

// ---- helpers ----
__device__ __forceinline__ void async_cp16(void* lds, const void* g) {
  __builtin_amdgcn_global_load_lds(
      (const __attribute__((address_space(1))) unsigned int*)g,
      (__attribute__((address_space(3))) unsigned int*)lds, 16, 0, 0);
}
// x ~ s*(q0 + q1/128), s = 1/20
__device__ __forceinline__ int q0_of(float x) {
  int q = __float2int_rn(x * 20.0f);
  return q > 127 ? 127 : (q < -127 ? -127 : q);
}
__device__ __forceinline__ int q1_of(float x, int q0) {
  float e = x * 20.0f - (float)q0;
  int q = __float2int_rn(e * 128.0f);
  return q > 127 ? 127 : (q < -127 ? -127 : q);
}
__device__ __forceinline__ unsigned int pack4(int a, int b, int c, int d) {
  return (unsigned int)(a & 0xff) | ((unsigned int)(b & 0xff) << 8) |
         ((unsigned int)(c & 0xff) << 16) | ((unsigned int)(d & 0xff) << 24);
}

// ---- kernel 1: quantize emb table to int8 q0/q1 + scaled int row sumsq ----
// iwsq2 = rint(wsq*25600) + 8192  (SC units = 1/25600, +bias)
__global__ __launch_bounds__(256) void prep_w_kernel(
    const float* __restrict__ emb, unsigned int* __restrict__ q0w,
    unsigned int* __restrict__ q1w, int* __restrict__ iwsq2) {
  int lane = threadIdx.x & 63;
  int row = blockIdx.x * 4 + (threadIdx.x >> 6);
  const float4 v = *(const float4*)(emb + (size_t)row * DIM + lane * 4);
  float s = v.x * v.x + v.y * v.y + v.z * v.z + v.w * v.w;
  int a0 = q0_of(v.x), b0 = q0_of(v.y), c0 = q0_of(v.z), d0 = q0_of(v.w);
  q0w[row * (DIM / 4) + lane] = pack4(a0, b0, c0, d0);
  q1w[row * (DIM / 4) + lane] =
      pack4(q1_of(v.x, a0), q1_of(v.y, b0), q1_of(v.z, c0), q1_of(v.w, d0));
#pragma unroll
  for (int off = 32; off > 0; off >>= 1) s += __shfl_xor(s, off, 64);
  if (lane == 0) iwsq2[row] = (int)rintf(s * 25600.0f) + 8192;
}

// ---- kernel 2: transpose z -> token-major int8 q0/q1 + token-major fp32 ----
__global__ __launch_bounds__(256) void prep_z_kernel(
    const float* __restrict__ z, unsigned int* __restrict__ q0z,
    unsigned int* __restrict__ q1z, float* __restrict__ zf32) {
  __shared__ float tile[64][65];
  int b = blockIdx.x, d0 = blockIdx.y * 64, hw0 = blockIdx.z * 64;
  int tid = threadIdx.x;
  int lane = tid & 63, grp = tid >> 6;
  const float* src = z + (size_t)b * DIM * HW + hw0 + lane;
#pragma unroll
  for (int i = 0; i < 16; i++) {
    int dl = grp + i * 4;
    tile[dl][lane] = src[(size_t)(d0 + dl) * HW];  // coalesced along hw
  }
  __syncthreads();
  int dq = tid & 15;  // covers 4 d's
#pragma unroll
  for (int p = 0; p < 4; p++) {
    int n = (tid >> 4) + p * 16;  // hw_local
    float x0 = tile[dq * 4 + 0][n], x1 = tile[dq * 4 + 1][n];
    float x2 = tile[dq * 4 + 2][n], x3 = tile[dq * 4 + 3][n];
    int a0 = q0_of(x0), b0 = q0_of(x1), c0 = q0_of(x2), e0 = q0_of(x3);
    int token = b * HW + hw0 + n;
    size_t off = (size_t)token * (DIM / 4) + (d0 >> 2) + dq;
    q0z[off] = pack4(a0, b0, c0, e0);
    q1z[off] = pack4(q1_of(x0, a0), q1_of(x1, b0), q1_of(x2, c0), q1_of(x3, e0));
    *(float4*)(zf32 + (size_t)token * DIM + d0 + dq * 4) =
        make_float4(x0, x1, x2, x3);
  }
}

// ---- kernel 3: 256-thread phase-diverse GEMM + packed-u32 top-2 per kq ----
// block = 64 tokens x one 2048-code quarter; 64 iters of 32-code tiles.
// 32 KB LDS dbuf -> target 4 blocks/CU (phase-independent barriers).
// acc = 128*q0z.q0w + q0z.q1w + q1z.q0w ; score_int = iwsq2 - acc
// pack = ((clamp(score)>>6)<<13) | idx13
// NOTE (R5 lesson): launch_bounds VGPR cap must exceed live set or scratch
// spill (WRITE_SIZE explodes). Live set here ~110, cap 128.
__global__ __launch_bounds__(256, 4) void gemm_topk_kernel(
    const signed char* __restrict__ q0z, const signed char* __restrict__ q1z,
    const signed char* __restrict__ q0w, const signed char* __restrict__ q1w,
    const int* __restrict__ iwsq2, uint2* __restrict__ partials) {
  // [buf][arr: 0=q0w k0-127, 1=q0w k128-255, 2=q1w k0-127, 3=q1w k128-255]
  // 32 rows x 128 B per array; chunk t in row holds global chunk t^(row&7)
  // (exact R6 zero-conflict geometry, 32 rows instead of 64)
  __shared__ __align__(16) signed char sB[2][4][32 * 128];

  // XCD-aware: pin each code-quarter to one XCD pair (1 MB B set per L2).
  const int bid = blockIdx.x;  // 0..1023
  const int xcd = bid & 7;
  const int kq = xcd >> 1;                        // 0..3 code quarter
  const int tg = (bid >> 3) + ((xcd & 1) << 7);   // 0..255 token group
  const int tid = threadIdx.x;
  const int lane = tid & 63, w = tid >> 6;        // 4 waves: 16 tokens each
  const int c = lane & 15, quad = lane >> 4;
  const int n0 = tg * 64;
  const int k0g = kq * 2048;

  // A fragments: global -> registers, once. A[m=c][chunk=s*4+quad]
  int4v af0[4], af1[4];
  {
    const size_t arow = (size_t)(n0 + w * 16 + c) * DIM;
#pragma unroll
    for (int s = 0; s < 4; s++) {
      af0[s] = *(const int4v*)(q0z + arow + s * 64 + quad * 16);
      af1[s] = *(const int4v*)(q1z + arow + s * 64 + quad * 16);
    }
  }

  // staging pointers (swizzle on source, LDS dest linear in tid)
  const int srow = tid >> 3;
  const int scl = ((tid & 7) ^ (srow & 7)) * 16;
  const signed char* p0 = q0w + (size_t)(k0g + srow) * DIM + scl;
  const signed char* p1 = q1w + (size_t)(k0g + srow) * DIM + scl;
  async_cp16(&sB[0][0][tid * 16], p0);
  async_cp16(&sB[0][1][tid * 16], p0 + 128);
  async_cp16(&sB[0][2][tid * 16], p1);
  async_cp16(&sB[0][3][tid * 16], p1 + 128);
  p0 += 32 * DIM;
  p1 += 32 * DIM;
  __syncthreads();

  unsigned int m1[4], m2[4];
#pragma unroll
  for (int i = 0; i < 4; i++) { m1[i] = 0xFFFFFFFFu; m2[i] = 0xFFFFFFFFu; }

  unsigned int idx0 = (unsigned)(k0g + c);
  const int4v zero = {0, 0, 0, 0};

  for (int it = 0; it < 64; it++) {
    const int buf = it & 1;
    if (it + 1 < 64) {  // stage next tile (uniform guard, no OOB)
      const int nb = buf ^ 1;
      async_cp16(&sB[nb][0][tid * 16], p0);
      async_cp16(&sB[nb][1][tid * 16], p0 + 128);
      async_cp16(&sB[nb][2][tid * 16], p1);
      async_cp16(&sB[nb][3][tid * 16], p1 + 128);
      p0 += 32 * DIM;
      p1 += 32 * DIM;
    }
    const int iw0 = iwsq2[k0g + it * 32 + c];
    const int iw1 = iwsq2[k0g + it * 32 + 16 + c];

    // B q0 fragments for both 16-code cols (row = tn*16+c; row&7 == c&7)
    int4v b0a[4], b0b[4];
#pragma unroll
    for (int s = 0; s < 4; s++) {
      const int half = s >> 1;
      const int ph = ((((s & 1) << 2) + quad) ^ (c & 7)) * 16;
      b0a[s] = *(const int4v*)(&sB[buf][half][c * 128 + ph]);
      b0b[s] = *(const int4v*)(&sB[buf][half][(16 + c) * 128 + ph]);
    }
    int4v a0, a1;
    a0 = __builtin_amdgcn_mfma_i32_16x16x64_i8(af0[0], b0a[0], zero, 0, 0, 0);
    a1 = __builtin_amdgcn_mfma_i32_16x16x64_i8(af0[0], b0b[0], zero, 0, 0, 0);
#pragma unroll
    for (int s = 1; s < 4; s++) {
      a0 = __builtin_amdgcn_mfma_i32_16x16x64_i8(af0[s], b0a[s], a0, 0, 0, 0);
      a1 = __builtin_amdgcn_mfma_i32_16x16x64_i8(af0[s], b0b[s], a1, 0, 0, 0);
    }
#pragma unroll
    for (int r = 0; r < 4; r++) { a0[r] <<= 7; a1[r] <<= 7; }  // 128*P00
#pragma unroll
    for (int s = 0; s < 4; s++) {  // + P10 (reuses b0)
      a0 = __builtin_amdgcn_mfma_i32_16x16x64_i8(af1[s], b0a[s], a0, 0, 0, 0);
      a1 = __builtin_amdgcn_mfma_i32_16x16x64_i8(af1[s], b0b[s], a1, 0, 0, 0);
    }
#pragma unroll
    for (int s = 0; s < 4; s++) {  // + P01 (b1 loaded late: low reg pressure)
      const int half = s >> 1;
      const int ph = ((((s & 1) << 2) + quad) ^ (c & 7)) * 16;
      int4v t = *(const int4v*)(&sB[buf][2 + half][c * 128 + ph]);
      int4v u = *(const int4v*)(&sB[buf][2 + half][(16 + c) * 128 + ph]);
      a0 = __builtin_amdgcn_mfma_i32_16x16x64_i8(af0[s], t, a0, 0, 0, 0);
      a1 = __builtin_amdgcn_mfma_i32_16x16x64_i8(af0[s], u, a1, 0, 0, 0);
    }
    // epilogue: packed-u32 top-2 insert (C/D: col=lane&15, row=quad*4+r)
#pragma unroll
    for (int r = 0; r < 4; r++) {
      unsigned int s0 = (unsigned int)(iw0 - a0[r]);
      unsigned int s1 = (unsigned int)(iw1 - a1[r]);
      s0 = s0 < 0x2000000u ? s0 : 0x1FFFFFFu;
      s1 = s1 < 0x2000000u ? s1 : 0x1FFFFFFu;
      unsigned int pk0 = ((s0 << 7) & 0xFFFFE000u) | idx0;
      unsigned int pk1 = ((s1 << 7) & 0xFFFFE000u) | (idx0 + 16);
      unsigned int v = pk0 < pk1 ? pk0 : pk1;
      unsigned int lo = v < m1[r] ? v : m1[r];
      unsigned int hi = v < m1[r] ? m1[r] : v;
      m2[r] = m2[r] < hi ? m2[r] : hi;
      m1[r] = lo;
    }
    idx0 += 32;
    __syncthreads();  // drains next-tile staging (in flight all compute phase)
  }

  // merge top-2 across the 16 c-lanes (idx rides in low bits)
#pragma unroll
  for (int r = 0; r < 4; r++) {
    unsigned int a1m = m1[r], a2m = m2[r];
#pragma unroll
    for (int off = 1; off < 16; off <<= 1) {
      unsigned int o1 = __shfl_xor(a1m, off, 16);
      unsigned int o2 = __shfl_xor(a2m, off, 16);
      unsigned int n1 = a1m < o1 ? a1m : o1;
      unsigned int hi = a1m < o1 ? o1 : a1m;
      unsigned int l2 = a2m < o2 ? a2m : o2;
      a2m = hi < l2 ? hi : l2;
      a1m = n1;
    }
    m1[r] = a1m;
    m2[r] = a2m;
  }
  if (c == 0) {
#pragma unroll
    for (int r = 0; r < 4; r++) {
      int token = n0 + w * 16 + quad * 4 + r;
      partials[(size_t)kq * NTOK + token] = make_uint2(m1[r], m2[r]);
    }
  }
}

// ---- kernel 4: approx-filtered exact rescore ----
// 8 distinct candidates (top-2 x 4 quarters). Survivor = packed score within
// 64 units (~26 sigma of i8 approx error) of min. 1 survivor (99% of tokens):
// emit directly, zero loads. Else fp64-rescore survivors.
__global__ __launch_bounds__(256) void rescore_kernel(
    const uint2* __restrict__ partials, const float* __restrict__ zf32,
    const float* __restrict__ emb, int* __restrict__ ids) {
  int w = threadIdx.x >> 6, lane = threadIdx.x & 63;
  int token = blockIdx.x * 4 + w;
  unsigned int p[8];
#pragma unroll
  for (int q = 0; q < 4; q++) {
    uint2 t = partials[(size_t)q * NTOK + token];
    p[q * 2] = t.x;
    p[q * 2 + 1] = t.y;
  }
  unsigned int smin = p[0];
#pragma unroll
  for (int q = 1; q < 8; q++) smin = p[q] < smin ? p[q] : smin;
  const unsigned int thr = (smin >> 13) + 64;
  int ns = 0;
#pragma unroll
  for (int q = 0; q < 8; q++) ns += ((p[q] >> 13) <= thr) ? 1 : 0;
  if (ns == 1) {  // wave-uniform
    if (lane == 0) ids[token] = (int)(smin & 0x1FFFu);
    return;
  }
  const float4 zv = *(const float4*)(zf32 + (size_t)token * DIM + lane * 4);
  double best = 1e300;
  int bid = NEMB;
#pragma unroll
  for (int q = 0; q < 8; q++) {
    if ((p[q] >> 13) <= thr) {  // wave-uniform
      int id = (int)(p[q] & 0x1FFFu);
      const float4 wv = *(const float4*)(emb + (size_t)id * DIM + lane * 4);
      double s = (double)wv.x * ((double)wv.x - 2.0 * (double)zv.x) +
                 (double)wv.y * ((double)wv.y - 2.0 * (double)zv.y) +
                 (double)wv.z * ((double)wv.z - 2.0 * (double)zv.z) +
                 (double)wv.w * ((double)wv.w - 2.0 * (double)zv.w);
#pragma unroll
      for (int off = 32; off > 0; off >>= 1) s += __shfl_xor(s, off, 64);
      if (s < best || (s == best && id < bid)) {
        best = s;
        bid = id;
      }
    }
  }
  if (lane == 0) ids[token] = bid;
}

// ---- kernel 5: gather emb rows, transpose to [B,D,H,W] via LDS ----
__global__ __launch_bounds__(256) void gather_kernel(
    const int* __restrict__ ids, const float* __restrict__ emb,
    float* __restrict__ out) {
  __shared__ float tile[32][257];
  __shared__ int sid[32];
  int b = blockIdx.x;
  int hw0 = blockIdx.y * 32;
  int tid = threadIdx.x;
  if (tid < 32) sid[tid] = ids[b * HW + hw0 + tid];
  __syncthreads();
  for (int i = 0; i < 32; i++)
    tile[i][tid] = emb[(size_t)sid[i] * DIM + tid];  // coalesced 1KB row loads
  __syncthreads();
  int h = tid & 31, dg = tid >> 5;
  for (int i = 0; i < 32; i++) {
    int d = i * 8 + dg;
    out[(size_t)b * DIM * HW + (size_t)d * HW + hw0 + h] = tile[h][d];
  }
}

extern "C" void kernel_launch(void* const* d_in, const int* in_sizes, int n_in,
                              void* d_out, int out_size, void* d_ws, size_t ws_size,
                              hipStream_t stream) {
  const float* z = (const float*)d_in[0];    // [16,256,32,32]
  const float* emb = (const float*)d_in[1];  // [8192,256]
  float* out = (float*)d_out;
  char* ws = (char*)d_ws;

  // zf32 (16 MB) lives in d_out — dead until gather overwrites it.
  float* zf32 = (float*)d_out;

  // ws: q0w 2M | q1w 2M | q0z 4M | q1z 4M | iwsq2 32K | partials 512K | ids 64K
  signed char* q0w = (signed char*)(ws);
  signed char* q1w = (signed char*)(ws + 2097152);
  signed char* q0z = (signed char*)(ws + 4194304);
  signed char* q1z = (signed char*)(ws + 8388608);
  int* iwsq2 = (int*)(ws + 12582912);
  uint2* partials = (uint2*)(ws + 12615680);
  int* ids = (int*)(ws + 13139968);

  prep_w_kernel<<<dim3(2048), 256, 0, stream>>>(emb, (unsigned int*)q0w,
                                                (unsigned int*)q1w, iwsq2);
  prep_z_kernel<<<dim3(16, 4, 16), 256, 0, stream>>>(z, (unsigned int*)q0z,
                                                     (unsigned int*)q1z, zf32);
  gemm_topk_kernel<<<dim3(1024), 256, 0, stream>>>(q0z, q1z, q0w, q1w, iwsq2,
                                                   partials);
  rescore_kernel<<<dim3(4096), 256, 0, stream>>>(partials, zf32, emb, ids);
  gather_kernel<<<dim3(16, 32), 256, 0, stream>>>(ids, emb, out);
}

// Round 8
// 185.877 us; speedup vs baseline: 2.6036x; 1.0304x over previous
//
#include <hip/hip_runtime.h>
#include <stdint.h>

#define DIM 256
#define NEMB 8192
#define NTOK 16384
#define HW 1024

typedef __attribute__((ext_vector_type(4))) int int4v;

// ---- helpers ----
__device__ __forceinline__ void async_cp16(void* lds, const void* g) {
  __builtin_amdgcn_global_load_lds(
      (const __attribute__((address_space(1))) unsigned int*)g,
      (__attribute__((address_space(3))) unsigned int*)lds, 16, 0, 0);
}
// x ~ s*(q0 + q1/128), s = 1/20
__device__ __forceinline__ int q0_of(float x) {
  int q = __float2int_rn(x * 20.0f);
  return q > 127 ? 127 : (q < -127 ? -127 : q);
}
__device__ __forceinline__ int q1_of(float x, int q0) {
  float e = x * 20.0f - (float)q0;
  int q = __float2int_rn(e * 128.0f);
  return q > 127 ? 127 : (q < -127 ? -127 : q);
}
__device__ __forceinline__ unsigned int pack4(int a, int b, int c, int d) {
  return (unsigned int)(a & 0xff) | ((unsigned int)(b & 0xff) << 8) |
         ((unsigned int)(c & 0xff) << 16) | ((unsigned int)(d & 0xff) << 24);
}

// ---- kernel 1: merged prep (w-quant + z-transpose/quant) ----
// blocks 0..2047: emb -> q0w/q1w/iwsq2 ; blocks 2048..3071: z -> q0z/q1z
__global__ __launch_bounds__(256) void prep_kernel(
    const float* __restrict__ emb, unsigned int* __restrict__ q0w,
    unsigned int* __restrict__ q1w, int* __restrict__ iwsq2,
    const float* __restrict__ z, unsigned int* __restrict__ q0z,
    unsigned int* __restrict__ q1z) {
  __shared__ float tile[64][65];
  int tid = threadIdx.x;
  int lane = tid & 63;
  if (blockIdx.x < 2048) {
    int row = blockIdx.x * 4 + (tid >> 6);
    const float4 v = *(const float4*)(emb + (size_t)row * DIM + lane * 4);
    float s = v.x * v.x + v.y * v.y + v.z * v.z + v.w * v.w;
    int a0 = q0_of(v.x), b0 = q0_of(v.y), c0 = q0_of(v.z), d0 = q0_of(v.w);
    q0w[row * (DIM / 4) + lane] = pack4(a0, b0, c0, d0);
    q1w[row * (DIM / 4) + lane] =
        pack4(q1_of(v.x, a0), q1_of(v.y, b0), q1_of(v.z, c0), q1_of(v.w, d0));
#pragma unroll
    for (int off = 32; off > 0; off >>= 1) s += __shfl_xor(s, off, 64);
    if (lane == 0) iwsq2[row] = (int)rintf(s * 25600.0f) + 8192;
    return;
  }
  int idx = blockIdx.x - 2048;
  int b = idx >> 6, d0 = ((idx >> 4) & 3) * 64, hw0 = (idx & 15) * 64;
  int grp = tid >> 6;
  const float* src = z + (size_t)b * DIM * HW + hw0 + lane;
#pragma unroll
  for (int i = 0; i < 16; i++) {
    int dl = grp + i * 4;
    tile[dl][lane] = src[(size_t)(d0 + dl) * HW];  // coalesced along hw
  }
  __syncthreads();
  int dq = tid & 15;  // covers 4 d's
#pragma unroll
  for (int p = 0; p < 4; p++) {
    int n = (tid >> 4) + p * 16;  // hw_local
    float x0 = tile[dq * 4 + 0][n], x1 = tile[dq * 4 + 1][n];
    float x2 = tile[dq * 4 + 2][n], x3 = tile[dq * 4 + 3][n];
    int a0 = q0_of(x0), b0 = q0_of(x1), c0 = q0_of(x2), e0 = q0_of(x3);
    int token = b * HW + hw0 + n;
    size_t off = (size_t)token * (DIM / 4) + (d0 >> 2) + dq;
    q0z[off] = pack4(a0, b0, c0, e0);
    q1z[off] = pack4(q1_of(x0, a0), q1_of(x1, b0), q1_of(x2, c0), q1_of(x3, e0));
  }
}

// ---- kernel 2: high-reuse GEMM + packed-u32 top-2 per code-eighth ----
// block = 128 threads (2 waves); wave = 64 tokens x 16 codes/iter;
// 64 iters over one 1024-code eighth. A in registers (4 token-tiles),
// each B fragment feeds 12 MFMAs -> LDS reads ~1/6 of R7.
// acc = 128*q0z.q0w + q0z.q1w + q1z.q0w ; score_int = iwsq2 - acc
// pack = ((clamp(score)>>6)<<13) | idx13
// R5 lesson: VGPR cap (here 256 via (128,2)) must exceed live set (~220)
// or scratch spill (WRITE_SIZE explodes).
__global__ __launch_bounds__(128, 2) void gemm_topk_kernel(
    const signed char* __restrict__ q0z, const signed char* __restrict__ q1z,
    const signed char* __restrict__ q0w, const signed char* __restrict__ q1w,
    const int* __restrict__ iwsq2, uint2* __restrict__ partials) {
  // [buf][arr: 0=q0w k0-127, 1=q0w k128-255, 2=q1w k0-127, 3=q1w k128-255]
  // 16 rows x 128 B per array; chunk t in row holds global chunk t^(row&7)
  // (R6/R7 zero-conflict geometry, 16 rows)
  __shared__ __align__(16) signed char sB[2][4][16 * 128];

  const int bid = blockIdx.x;   // 0..1023
  const int kq = bid & 7;       // code eighth, pinned per XCD
  const int tg = bid >> 3;      // 0..127 token group (128 tokens)
  const int tid = threadIdx.x;
  const int lane = tid & 63, w = tid >> 6;  // 2 waves x 64 tokens
  const int c = lane & 15, quad = lane >> 4;
  const int n0 = tg * 128;
  const int k0g = kq * 1024;

  // A fragments: global -> registers, once. tile t: rows n0+w*64+t*16+c
  int4v af0[4][4], af1[4][4];
#pragma unroll
  for (int t = 0; t < 4; t++) {
    const size_t arow = (size_t)(n0 + w * 64 + t * 16 + c) * DIM;
#pragma unroll
    for (int s = 0; s < 4; s++) {
      af0[t][s] = *(const int4v*)(q0z + arow + s * 64 + quad * 16);
      af1[t][s] = *(const int4v*)(q1z + arow + s * 64 + quad * 16);
    }
  }

  // staging: 128 chunks per array, thread tid handles chunk tid
  const int srow = tid >> 3;                     // 0..15
  const int scl = ((tid & 7) ^ (srow & 7)) * 16; // source chunk (swizzled)
  const signed char* p0 = q0w + (size_t)(k0g + srow) * DIM + scl;
  const signed char* p1 = q1w + (size_t)(k0g + srow) * DIM + scl;
  async_cp16(&sB[0][0][tid * 16], p0);
  async_cp16(&sB[0][1][tid * 16], p0 + 128);
  async_cp16(&sB[0][2][tid * 16], p1);
  async_cp16(&sB[0][3][tid * 16], p1 + 128);
  p0 += 16 * DIM;
  p1 += 16 * DIM;
  __syncthreads();

  unsigned int m1[16], m2[16];
#pragma unroll
  for (int i = 0; i < 16; i++) { m1[i] = 0xFFFFFFFFu; m2[i] = 0xFFFFFFFFu; }

  unsigned int idx0 = (unsigned)(k0g + c);
  const int4v zero = {0, 0, 0, 0};

  for (int it = 0; it < 64; it++) {
    const int buf = it & 1;
    if (it + 1 < 64) {  // stage next 16-code tile into other buffer
      const int nb = buf ^ 1;
      async_cp16(&sB[nb][0][tid * 16], p0);
      async_cp16(&sB[nb][1][tid * 16], p0 + 128);
      async_cp16(&sB[nb][2][tid * 16], p1);
      async_cp16(&sB[nb][3][tid * 16], p1 + 128);
      p0 += 16 * DIM;
      p1 += 16 * DIM;
    }
    const int iw = iwsq2[k0g + it * 16 + c];  // L1-hot

    // B q0 fragments (row = c; row&7 == c&7)
    int4v b0[4];
#pragma unroll
    for (int s = 0; s < 4; s++) {
      const int ph = ((((s & 1) << 2) + quad) ^ (c & 7)) * 16;
      b0[s] = *(const int4v*)(&sB[buf][s >> 1][c * 128 + ph]);
    }
    int4v a[4];
    // P00 (chain per tile, 4 independent tiles)
#pragma unroll
    for (int t = 0; t < 4; t++) {
      a[t] = __builtin_amdgcn_mfma_i32_16x16x64_i8(af0[t][0], b0[0], zero, 0, 0, 0);
#pragma unroll
      for (int s = 1; s < 4; s++)
        a[t] = __builtin_amdgcn_mfma_i32_16x16x64_i8(af0[t][s], b0[s], a[t], 0, 0, 0);
    }
#pragma unroll
    for (int t = 0; t < 4; t++)
#pragma unroll
      for (int r = 0; r < 4; r++) a[t][r] <<= 7;  // 128*P00
    // P10 (af1 x b0; b0 dies after)
#pragma unroll
    for (int t = 0; t < 4; t++)
#pragma unroll
      for (int s = 0; s < 4; s++)
        a[t] = __builtin_amdgcn_mfma_i32_16x16x64_i8(af1[t][s], b0[s], a[t], 0, 0, 0);
    // P01 (af0 x b1; b1 loaded late -> low pressure)
#pragma unroll
    for (int s = 0; s < 4; s++) {
      const int ph = ((((s & 1) << 2) + quad) ^ (c & 7)) * 16;
      int4v b1 = *(const int4v*)(&sB[buf][2 + (s >> 1)][c * 128 + ph]);
#pragma unroll
      for (int t = 0; t < 4; t++)
        a[t] = __builtin_amdgcn_mfma_i32_16x16x64_i8(af0[t][s], b1, a[t], 0, 0, 0);
    }
    // epilogue: packed-u32 top-2 insert (C/D: col=lane&15, row=quad*4+r)
#pragma unroll
    for (int t = 0; t < 4; t++) {
#pragma unroll
      for (int r = 0; r < 4; r++) {
        unsigned int s0 = (unsigned int)(iw - a[t][r]);
        s0 = s0 < 0x2000000u ? s0 : 0x1FFFFFFu;
        unsigned int v = ((s0 << 7) & 0xFFFFE000u) | idx0;
        const int ix = t * 4 + r;
        unsigned int lo = v < m1[ix] ? v : m1[ix];
        unsigned int hi = v < m1[ix] ? m1[ix] : v;
        m2[ix] = m2[ix] < hi ? m2[ix] : hi;
        m1[ix] = lo;
      }
    }
    idx0 += 16;
    __syncthreads();  // drains next-tile staging (in flight all compute phase)
  }

  // merge top-2 across the 16 c-lanes (idx rides in low bits)
#pragma unroll
  for (int ix = 0; ix < 16; ix++) {
    unsigned int a1m = m1[ix], a2m = m2[ix];
#pragma unroll
    for (int off = 1; off < 16; off <<= 1) {
      unsigned int o1 = __shfl_xor(a1m, off, 16);
      unsigned int o2 = __shfl_xor(a2m, off, 16);
      unsigned int n1 = a1m < o1 ? a1m : o1;
      unsigned int hi = a1m < o1 ? o1 : a1m;
      unsigned int l2 = a2m < o2 ? a2m : o2;
      a2m = hi < l2 ? hi : l2;
      a1m = n1;
    }
    m1[ix] = a1m;
    m2[ix] = a2m;
  }
  if (c == 0) {
#pragma unroll
    for (int t = 0; t < 4; t++) {
#pragma unroll
      for (int r = 0; r < 4; r++) {
        int token = n0 + w * 64 + t * 16 + quad * 4 + r;
        partials[(size_t)kq * NTOK + token] =
            make_uint2(m1[t * 4 + r], m2[t * 4 + r]);
      }
    }
  }
}

// ---- kernel 3: fused filter/rescore + gather/transpose ----
// 16 distinct candidates (top-2 x 8 eighths). Survivor within 64 packed
// units of min; 1 survivor (~99%): zero loads. Else fp64 rescore (reads
// strided z directly - rare). Then gather winners -> [B,D,H,W].
__global__ __launch_bounds__(256) void rescore_gather_kernel(
    const uint2* __restrict__ partials, const float* __restrict__ z,
    const float* __restrict__ emb, float* __restrict__ out) {
  __shared__ float tile[32][257];
  __shared__ int sid[32];
  const int b = blockIdx.x >> 5;
  const int hw0 = (blockIdx.x & 31) * 32;
  const int tid = threadIdx.x;
  const int w = tid >> 6, lane = tid & 63;
  // phase 1: each wave resolves 8 tokens
  for (int i = 0; i < 8; i++) {
    const int tl = w * 8 + i;
    const int token = b * HW + hw0 + tl;
    unsigned int p[16];
#pragma unroll
    for (int q = 0; q < 8; q++) {
      uint2 t = partials[(size_t)q * NTOK + token];
      p[q * 2] = t.x;
      p[q * 2 + 1] = t.y;
    }
    unsigned int smin = p[0];
#pragma unroll
    for (int q = 1; q < 16; q++) smin = p[q] < smin ? p[q] : smin;
    const unsigned int thr = (smin >> 13) + 64;
    int ns = 0;
#pragma unroll
    for (int q = 0; q < 16; q++) ns += ((p[q] >> 13) <= thr) ? 1 : 0;
    int chosen = (int)(smin & 0x1FFFu);
    if (ns > 1) {  // wave-uniform rare path: exact fp64
      float zv[4];
#pragma unroll
      for (int j = 0; j < 4; j++)
        zv[j] = z[(size_t)b * DIM * HW + (size_t)(lane * 4 + j) * HW + hw0 + tl];
      double best = 1e300;
      int bid2 = NEMB;
#pragma unroll
      for (int q = 0; q < 16; q++) {
        if ((p[q] >> 13) <= thr) {
          int id = (int)(p[q] & 0x1FFFu);
          const float4 wv = *(const float4*)(emb + (size_t)id * DIM + lane * 4);
          double s = (double)wv.x * ((double)wv.x - 2.0 * (double)zv[0]) +
                     (double)wv.y * ((double)wv.y - 2.0 * (double)zv[1]) +
                     (double)wv.z * ((double)wv.z - 2.0 * (double)zv[2]) +
                     (double)wv.w * ((double)wv.w - 2.0 * (double)zv[3]);
#pragma unroll
          for (int off = 32; off > 0; off >>= 1) s += __shfl_xor(s, off, 64);
          if (s < best || (s == best && id < bid2)) {
            best = s;
            bid2 = id;
          }
        }
      }
      chosen = bid2;
    }
    if (lane == 0) sid[tl] = chosen;
  }
  __syncthreads();
  // phase 2: gather + transpose (R7-proven)
  for (int i = 0; i < 32; i++)
    tile[i][tid] = emb[(size_t)sid[i] * DIM + tid];  // coalesced 1KB row loads
  __syncthreads();
  int h = tid & 31, dg = tid >> 5;
  for (int i = 0; i < 32; i++) {
    int d = i * 8 + dg;
    out[(size_t)b * DIM * HW + (size_t)d * HW + hw0 + h] = tile[h][d];
  }
}

extern "C" void kernel_launch(void* const* d_in, const int* in_sizes, int n_in,
                              void* d_out, int out_size, void* d_ws, size_t ws_size,
                              hipStream_t stream) {
  const float* z = (const float*)d_in[0];    // [16,256,32,32]
  const float* emb = (const float*)d_in[1];  // [8192,256]
  float* out = (float*)d_out;
  char* ws = (char*)d_ws;

  // ws: q0w 2M | q1w 2M | q0z 4M | q1z 4M | iwsq2 32K | partials 1M
  signed char* q0w = (signed char*)(ws);
  signed char* q1w = (signed char*)(ws + 2097152);
  signed char* q0z = (signed char*)(ws + 4194304);
  signed char* q1z = (signed char*)(ws + 8388608);
  int* iwsq2 = (int*)(ws + 12582912);
  uint2* partials = (uint2*)(ws + 12615680);

  prep_kernel<<<dim3(3072), 256, 0, stream>>>(
      emb, (unsigned int*)q0w, (unsigned int*)q1w, iwsq2, z, (unsigned int*)q0z,
      (unsigned int*)q1z);
  gemm_topk_kernel<<<dim3(1024), 128, 0, stream>>>(q0z, q1z, q0w, q1w, iwsq2,
                                                   partials);
  rescore_gather_kernel<<<dim3(512), 256, 0, stream>>>(partials, z, emb, out);
}

// Round 9
// 172.642 us; speedup vs baseline: 2.8032x; 1.0767x over previous
//
#include <hip/hip_runtime.h>
#include <stdint.h>

#define DIM 256
#define NEMB 8192
#define NTOK 16384
#define HW 1024

typedef __attribute__((ext_vector_type(4))) int int4v;

// ---- helpers ----
__device__ __forceinline__ void async_cp16(void* lds, const void* g) {
  __builtin_amdgcn_global_load_lds(
      (const __attribute__((address_space(1))) unsigned int*)g,
      (__attribute__((address_space(3))) unsigned int*)lds, 16, 0, 0);
}
// x ~ s*(q0 + q1/128), s = 1/20
__device__ __forceinline__ int q0_of(float x) {
  int q = __float2int_rn(x * 20.0f);
  return q > 127 ? 127 : (q < -127 ? -127 : q);
}
__device__ __forceinline__ int q1_of(float x, int q0) {
  float e = x * 20.0f - (float)q0;
  int q = __float2int_rn(e * 128.0f);
  return q > 127 ? 127 : (q < -127 ? -127 : q);
}
__device__ __forceinline__ unsigned int pack4(int a, int b, int c, int d) {
  return (unsigned int)(a & 0xff) | ((unsigned int)(b & 0xff) << 8) |
         ((unsigned int)(c & 0xff) << 16) | ((unsigned int)(d & 0xff) << 24);
}
// top-2 insert: new m2 = median(m1,m2,v); new m1 = min(m1,v). 2 VALU ops.
__device__ __forceinline__ void top2_insert(unsigned int v, unsigned int& m1,
                                            unsigned int& m2) {
  unsigned int med;
  asm("v_med3_u32 %0, %1, %2, %3" : "=v"(med) : "v"(v), "v"(m1), "v"(m2));
  m2 = med;
  m1 = v < m1 ? v : m1;
}

// ---- kernel 1: merged prep (w-quant + z-transpose/quant) ----
__global__ __launch_bounds__(256) void prep_kernel(
    const float* __restrict__ emb, unsigned int* __restrict__ q0w,
    unsigned int* __restrict__ q1w, int* __restrict__ iwsq2,
    const float* __restrict__ z, unsigned int* __restrict__ q0z,
    unsigned int* __restrict__ q1z) {
  __shared__ float tile[64][65];
  int tid = threadIdx.x;
  int lane = tid & 63;
  if (blockIdx.x < 2048) {
    int row = blockIdx.x * 4 + (tid >> 6);
    const float4 v = *(const float4*)(emb + (size_t)row * DIM + lane * 4);
    float s = v.x * v.x + v.y * v.y + v.z * v.z + v.w * v.w;
    int a0 = q0_of(v.x), b0 = q0_of(v.y), c0 = q0_of(v.z), d0 = q0_of(v.w);
    q0w[row * (DIM / 4) + lane] = pack4(a0, b0, c0, d0);
    q1w[row * (DIM / 4) + lane] =
        pack4(q1_of(v.x, a0), q1_of(v.y, b0), q1_of(v.z, c0), q1_of(v.w, d0));
#pragma unroll
    for (int off = 32; off > 0; off >>= 1) s += __shfl_xor(s, off, 64);
    if (lane == 0) iwsq2[row] = (int)rintf(s * 25600.0f) + 8192;
    return;
  }
  int idx = blockIdx.x - 2048;
  int b = idx >> 6, d0 = ((idx >> 4) & 3) * 64, hw0 = (idx & 15) * 64;
  int grp = tid >> 6;
  const float* src = z + (size_t)b * DIM * HW + hw0 + lane;
#pragma unroll
  for (int i = 0; i < 16; i++) {
    int dl = grp + i * 4;
    tile[dl][lane] = src[(size_t)(d0 + dl) * HW];  // coalesced along hw
  }
  __syncthreads();
  int dq = tid & 15;  // covers 4 d's
#pragma unroll
  for (int p = 0; p < 4; p++) {
    int n = (tid >> 4) + p * 16;  // hw_local
    float x0 = tile[dq * 4 + 0][n], x1 = tile[dq * 4 + 1][n];
    float x2 = tile[dq * 4 + 2][n], x3 = tile[dq * 4 + 3][n];
    int a0 = q0_of(x0), b0 = q0_of(x1), c0 = q0_of(x2), e0 = q0_of(x3);
    int token = b * HW + hw0 + n;
    size_t off = (size_t)token * (DIM / 4) + (d0 >> 2) + dq;
    q0z[off] = pack4(a0, b0, c0, e0);
    q1z[off] = pack4(q1_of(x0, a0), q1_of(x1, b0), q1_of(x2, c0), q1_of(x3, e0));
  }
}

// ---- kernel 2: GEMM + packed-u32 top-2 per code-eighth ----
// block = 256 threads (4 waves); wave = 32 tokens (2 tiles) x 32 codes/iter
// (2 cols); 32 iters over one 1024-code eighth. A in registers (64 VGPR).
// acc = 128*q0z.q0w + q0z.q1w + q1z.q0w ; score_int = iwsq2 - acc
// pack = ((clamp(score)>>6)<<13) | idx13
// R5 lesson: VGPR cap (170 via (256,3)) must exceed live set (~160) or
// scratch spill (WRITE_SIZE explodes -> check counter).
__global__ __launch_bounds__(256, 3) void gemm_topk_kernel(
    const signed char* __restrict__ q0z, const signed char* __restrict__ q1z,
    const signed char* __restrict__ q0w, const signed char* __restrict__ q1w,
    const int* __restrict__ iwsq2, uint2* __restrict__ partials) {
  // [buf][arr: 0=q0w k0-127, 1=q0w k128-255, 2=q1w k0-127, 3=q1w k128-255]
  // 32 rows x 128 B per array; slot t in row holds global chunk t^(row&7)
  // (R6/R7/R8-proven zero-conflict geometry)
  __shared__ __align__(16) signed char sB[2][4][32 * 128];

  const int bid = blockIdx.x;   // 0..1023
  const int kq = bid & 7;       // code eighth, pinned per XCD
  const int tg = bid >> 3;      // 0..127 token group (128 tokens)
  const int tid = threadIdx.x;
  const int lane = tid & 63, w = tid >> 6;  // 4 waves x 32 tokens
  const int c = lane & 15, quad = lane >> 4;
  const int n0 = tg * 128;
  const int k0g = kq * 1024;

  // A fragments: global -> registers, once. tile t: rows n0+w*32+t*16+c
  int4v af0[2][4], af1[2][4];
#pragma unroll
  for (int t = 0; t < 2; t++) {
    const size_t arow = (size_t)(n0 + w * 32 + t * 16 + c) * DIM;
#pragma unroll
    for (int s = 0; s < 4; s++) {
      af0[t][s] = *(const int4v*)(q0z + arow + s * 64 + quad * 16);
      af1[t][s] = *(const int4v*)(q1z + arow + s * 64 + quad * 16);
    }
  }

  // staging: 256 chunks per array, thread tid stages chunk tid
  const int srow = tid >> 3;                      // 0..31
  const int scl = ((tid & 7) ^ (srow & 7)) * 16;  // source chunk (swizzled)
  const signed char* p0 = q0w + (size_t)(k0g + srow) * DIM + scl;
  const signed char* p1 = q1w + (size_t)(k0g + srow) * DIM + scl;
  async_cp16(&sB[0][0][tid * 16], p0);
  async_cp16(&sB[0][1][tid * 16], p0 + 128);
  async_cp16(&sB[0][2][tid * 16], p1);
  async_cp16(&sB[0][3][tid * 16], p1 + 128);
  p0 += 32 * DIM;
  p1 += 32 * DIM;
  __syncthreads();

  unsigned int m1[8], m2[8];
#pragma unroll
  for (int i = 0; i < 8; i++) { m1[i] = 0xFFFFFFFFu; m2[i] = 0xFFFFFFFFu; }

  unsigned int idxA = (unsigned)(k0g + c);
  const int4v zero = {0, 0, 0, 0};

  for (int it = 0; it < 32; it++) {
    const int buf = it & 1;
    if (it + 1 < 32) {  // stage next 32-code tile into other buffer
      const int nb = buf ^ 1;
      async_cp16(&sB[nb][0][tid * 16], p0);
      async_cp16(&sB[nb][1][tid * 16], p0 + 128);
      async_cp16(&sB[nb][2][tid * 16], p1);
      async_cp16(&sB[nb][3][tid * 16], p1 + 128);
      p0 += 32 * DIM;
      p1 += 32 * DIM;
    }
    const int iw0 = iwsq2[k0g + it * 32 + c];       // L1-hot
    const int iw1 = iwsq2[k0g + it * 32 + 16 + c];

    // B q0 fragments for both cols (rows c and 16+c; (16+c)&7 == c&7)
    int4v b0a[4], b0b[4];
#pragma unroll
    for (int s = 0; s < 4; s++) {
      const int ph = ((((s & 1) << 2) + quad) ^ (c & 7)) * 16;
      b0a[s] = *(const int4v*)(&sB[buf][s >> 1][c * 128 + ph]);
      b0b[s] = *(const int4v*)(&sB[buf][s >> 1][(16 + c) * 128 + ph]);
    }
    int4v a[2][2];
    // P00
#pragma unroll
    for (int t = 0; t < 2; t++) {
      a[t][0] = __builtin_amdgcn_mfma_i32_16x16x64_i8(af0[t][0], b0a[0], zero, 0, 0, 0);
      a[t][1] = __builtin_amdgcn_mfma_i32_16x16x64_i8(af0[t][0], b0b[0], zero, 0, 0, 0);
#pragma unroll
      for (int s = 1; s < 4; s++) {
        a[t][0] = __builtin_amdgcn_mfma_i32_16x16x64_i8(af0[t][s], b0a[s], a[t][0], 0, 0, 0);
        a[t][1] = __builtin_amdgcn_mfma_i32_16x16x64_i8(af0[t][s], b0b[s], a[t][1], 0, 0, 0);
      }
    }
#pragma unroll
    for (int t = 0; t < 2; t++)
#pragma unroll
      for (int cn = 0; cn < 2; cn++)
#pragma unroll
        for (int r = 0; r < 4; r++) a[t][cn][r] <<= 7;  // 128*P00
    // P10 (af1 x b0; b0 dies after)
#pragma unroll
    for (int t = 0; t < 2; t++)
#pragma unroll
      for (int s = 0; s < 4; s++) {
        a[t][0] = __builtin_amdgcn_mfma_i32_16x16x64_i8(af1[t][s], b0a[s], a[t][0], 0, 0, 0);
        a[t][1] = __builtin_amdgcn_mfma_i32_16x16x64_i8(af1[t][s], b0b[s], a[t][1], 0, 0, 0);
      }
    // P01 (af0 x b1; b1 loaded late -> low pressure)
#pragma unroll
    for (int s = 0; s < 4; s++) {
      const int ph = ((((s & 1) << 2) + quad) ^ (c & 7)) * 16;
      int4v b1a = *(const int4v*)(&sB[buf][2 + (s >> 1)][c * 128 + ph]);
      int4v b1b = *(const int4v*)(&sB[buf][2 + (s >> 1)][(16 + c) * 128 + ph]);
#pragma unroll
      for (int t = 0; t < 2; t++) {
        a[t][0] = __builtin_amdgcn_mfma_i32_16x16x64_i8(af0[t][s], b1a, a[t][0], 0, 0, 0);
        a[t][1] = __builtin_amdgcn_mfma_i32_16x16x64_i8(af0[t][s], b1b, a[t][1], 0, 0, 0);
      }
    }
    // epilogue (C/D: col=lane&15, row=quad*4+r); col-pair min then top-2
#pragma unroll
    for (int t = 0; t < 2; t++) {
#pragma unroll
      for (int r = 0; r < 4; r++) {
        unsigned int s0 = (unsigned int)(iw0 - a[t][0][r]);
        unsigned int s1 = (unsigned int)(iw1 - a[t][1][r]);
        s0 = s0 < 0x2000000u ? s0 : 0x1FFFFFFu;
        s1 = s1 < 0x2000000u ? s1 : 0x1FFFFFFu;
        unsigned int pk0 = ((s0 << 7) & 0xFFFFE000u) | idxA;
        unsigned int pk1 = ((s1 << 7) & 0xFFFFE000u) | (idxA + 16);
        top2_insert(pk0 < pk1 ? pk0 : pk1, m1[t * 4 + r], m2[t * 4 + r]);
      }
    }
    idxA += 32;
    __syncthreads();  // drains next-tile staging (in flight all compute phase)
  }

  // merge top-2 across the 16 c-lanes (idx rides in low bits)
#pragma unroll
  for (int ix = 0; ix < 8; ix++) {
    unsigned int a1m = m1[ix], a2m = m2[ix];
#pragma unroll
    for (int off = 1; off < 16; off <<= 1) {
      unsigned int o1 = __shfl_xor(a1m, off, 16);
      unsigned int o2 = __shfl_xor(a2m, off, 16);
      unsigned int n1 = a1m < o1 ? a1m : o1;
      unsigned int hi = a1m < o1 ? o1 : a1m;
      unsigned int l2 = a2m < o2 ? a2m : o2;
      a2m = hi < l2 ? hi : l2;
      a1m = n1;
    }
    m1[ix] = a1m;
    m2[ix] = a2m;
  }
  if (c == 0) {
#pragma unroll
    for (int t = 0; t < 2; t++) {
#pragma unroll
      for (int r = 0; r < 4; r++) {
        int token = n0 + w * 32 + t * 16 + quad * 4 + r;
        partials[(size_t)kq * NTOK + token] =
            make_uint2(m1[t * 4 + r], m2[t * 4 + r]);
      }
    }
  }
}

// ---- kernel 3: parallel filter/rescore + gather/transpose ----
// phase 1: 8 threads per token (1 uint2 each), width-8 shuffle reduce;
// multi-survivor tokens -> LDS worklist, full-wave fp64 rescore (rare).
__global__ __launch_bounds__(256) void rescore_gather_kernel(
    const uint2* __restrict__ partials, const float* __restrict__ z,
    const float* __restrict__ emb, float* __restrict__ out) {
  __shared__ float tile[32][257];
  __shared__ int sid[32];
  __shared__ int wl[32];
  __shared__ int nwl;
  const int b = blockIdx.x >> 5;
  const int hw0 = (blockIdx.x & 31) * 32;
  const int tid = threadIdx.x;
  if (tid == 0) nwl = 0;
  __syncthreads();
  {
    const int tl = tid >> 3, sub = tid & 7;  // 32 tokens x 8 threads
    const int token = b * HW + hw0 + tl;
    uint2 e = partials[(size_t)sub * NTOK + token];
    unsigned int m = e.x < e.y ? e.x : e.y;
#pragma unroll
    for (int off = 1; off < 8; off <<= 1) {
      unsigned int o = __shfl_xor(m, off, 8);
      m = o < m ? o : m;
    }
    const unsigned int thr = (m >> 13) + 64;
    int cnt = (((e.x >> 13) <= thr) ? 1 : 0) + (((e.y >> 13) <= thr) ? 1 : 0);
#pragma unroll
    for (int off = 1; off < 8; off <<= 1) cnt += __shfl_xor(cnt, off, 8);
    if (sub == 0) {
      if (cnt == 1) {
        sid[tl] = (int)(m & 0x1FFFu);
      } else {
        int i = atomicAdd(&nwl, 1);
        wl[i] = tl;
      }
    }
  }
  __syncthreads();
  // rare fallback: one wave per worklist entry, exact fp64
  {
    const int w = tid >> 6, lane = tid & 63;
    for (int i = w; i < nwl; i += 4) {
      const int tl = wl[i];
      const int token = b * HW + hw0 + tl;
      unsigned int p[16];
#pragma unroll
      for (int q = 0; q < 8; q++) {
        uint2 t = partials[(size_t)q * NTOK + token];
        p[q * 2] = t.x;
        p[q * 2 + 1] = t.y;
      }
      unsigned int smin = p[0];
#pragma unroll
      for (int q = 1; q < 16; q++) smin = p[q] < smin ? p[q] : smin;
      const unsigned int thr = (smin >> 13) + 64;
      float zv[4];
#pragma unroll
      for (int j = 0; j < 4; j++)
        zv[j] = z[(size_t)b * DIM * HW + (size_t)(lane * 4 + j) * HW + hw0 + tl];
      double best = 1e300;
      int bid2 = NEMB;
#pragma unroll
      for (int q = 0; q < 16; q++) {
        if ((p[q] >> 13) <= thr) {
          int id = (int)(p[q] & 0x1FFFu);
          const float4 wv = *(const float4*)(emb + (size_t)id * DIM + lane * 4);
          double s = (double)wv.x * ((double)wv.x - 2.0 * (double)zv[0]) +
                     (double)wv.y * ((double)wv.y - 2.0 * (double)zv[1]) +
                     (double)wv.z * ((double)wv.z - 2.0 * (double)zv[2]) +
                     (double)wv.w * ((double)wv.w - 2.0 * (double)zv[3]);
#pragma unroll
          for (int off = 32; off > 0; off >>= 1) s += __shfl_xor(s, off, 64);
          if (s < best || (s == best && id < bid2)) {
            best = s;
            bid2 = id;
          }
        }
      }
      if (lane == 0) sid[tl] = bid2;
    }
  }
  __syncthreads();
  // phase 2: gather + transpose (R7/R8-proven)
  for (int i = 0; i < 32; i++)
    tile[i][tid] = emb[(size_t)sid[i] * DIM + tid];  // coalesced 1KB row loads
  __syncthreads();
  int h = tid & 31, dg = tid >> 5;
  for (int i = 0; i < 32; i++) {
    int d = i * 8 + dg;
    out[(size_t)b * DIM * HW + (size_t)d * HW + hw0 + h] = tile[h][d];
  }
}

extern "C" void kernel_launch(void* const* d_in, const int* in_sizes, int n_in,
                              void* d_out, int out_size, void* d_ws, size_t ws_size,
                              hipStream_t stream) {
  const float* z = (const float*)d_in[0];    // [16,256,32,32]
  const float* emb = (const float*)d_in[1];  // [8192,256]
  float* out = (float*)d_out;
  char* ws = (char*)d_ws;

  // ws: q0w 2M | q1w 2M | q0z 4M | q1z 4M | iwsq2 32K | partials 1M
  signed char* q0w = (signed char*)(ws);
  signed char* q1w = (signed char*)(ws + 2097152);
  signed char* q0z = (signed char*)(ws + 4194304);
  signed char* q1z = (signed char*)(ws + 8388608);
  int* iwsq2 = (int*)(ws + 12582912);
  uint2* partials = (uint2*)(ws + 12615680);

  prep_kernel<<<dim3(3072), 256, 0, stream>>>(
      emb, (unsigned int*)q0w, (unsigned int*)q1w, iwsq2, z, (unsigned int*)q0z,
      (unsigned int*)q1z);
  gemm_topk_kernel<<<dim3(1024), 256, 0, stream>>>(q0z, q1z, q0w, q1w, iwsq2,
                                                   partials);
  rescore_gather_kernel<<<dim3(512), 256, 0, stream>>>(partials, z, emb, out);
}

// Round 10
// 169.022 us; speedup vs baseline: 2.8632x; 1.0214x over previous
//
#include <hip/hip_runtime.h>
#include <stdint.h>

#define DIM 256
#define NEMB 8192
#define NTOK 16384
#define HW 1024

typedef __attribute__((ext_vector_type(4))) int int4v;

// ---- helpers ----
__device__ __forceinline__ void async_cp16(void* lds, const void* g) {
  __builtin_amdgcn_global_load_lds(
      (const __attribute__((address_space(1))) unsigned int*)g,
      (__attribute__((address_space(3))) unsigned int*)lds, 16, 0, 0);
}
// x ~ s*(q0 + q1/128), s = 1/20
__device__ __forceinline__ int q0_of(float x) {
  int q = __float2int_rn(x * 20.0f);
  return q > 127 ? 127 : (q < -127 ? -127 : q);
}
__device__ __forceinline__ int q1_of(float x, int q0) {
  float e = x * 20.0f - (float)q0;
  int q = __float2int_rn(e * 128.0f);
  return q > 127 ? 127 : (q < -127 ? -127 : q);
}
__device__ __forceinline__ unsigned int pack4(int a, int b, int c, int d) {
  return (unsigned int)(a & 0xff) | ((unsigned int)(b & 0xff) << 8) |
         ((unsigned int)(c & 0xff) << 16) | ((unsigned int)(d & 0xff) << 24);
}
__device__ __forceinline__ unsigned int med3u(unsigned int a, unsigned int b,
                                              unsigned int c) {
  unsigned int m;
  asm("v_med3_u32 %0, %1, %2, %3" : "=v"(m) : "v"(a), "v"(b), "v"(c));
  return m;
}
// sorted-triple insert: 1 min + 2 med3
__device__ __forceinline__ void top3_insert(unsigned int v, unsigned int& m1,
                                            unsigned int& m2, unsigned int& m3) {
  unsigned int t2 = med3u(v, m1, m2);
  unsigned int t3 = med3u(v, m2, m3);
  m1 = v < m1 ? v : m1;
  m2 = t2;
  m3 = t3;
}

// ---- kernel 1: merged prep (w-quant 2-term + z-quant 1-term coarse) ----
__global__ __launch_bounds__(256) void prep_kernel(
    const float* __restrict__ emb, unsigned int* __restrict__ q0w,
    unsigned int* __restrict__ q1w, int* __restrict__ iwsq2,
    const float* __restrict__ z, unsigned int* __restrict__ q0z) {
  __shared__ float tile[64][65];
  int tid = threadIdx.x;
  int lane = tid & 63;
  if (blockIdx.x < 2048) {
    int row = blockIdx.x * 4 + (tid >> 6);
    const float4 v = *(const float4*)(emb + (size_t)row * DIM + lane * 4);
    float s = v.x * v.x + v.y * v.y + v.z * v.z + v.w * v.w;
    int a0 = q0_of(v.x), b0 = q0_of(v.y), c0 = q0_of(v.z), d0 = q0_of(v.w);
    q0w[row * (DIM / 4) + lane] = pack4(a0, b0, c0, d0);
    q1w[row * (DIM / 4) + lane] =
        pack4(q1_of(v.x, a0), q1_of(v.y, b0), q1_of(v.z, c0), q1_of(v.w, d0));
#pragma unroll
    for (int off = 32; off > 0; off >>= 1) s += __shfl_xor(s, off, 64);
    if (lane == 0) iwsq2[row] = (int)rintf(s * 25600.0f) + 8192;
    return;
  }
  int idx = blockIdx.x - 2048;
  int b = idx >> 6, d0 = ((idx >> 4) & 3) * 64, hw0 = (idx & 15) * 64;
  int grp = tid >> 6;
  const float* src = z + (size_t)b * DIM * HW + hw0 + lane;
#pragma unroll
  for (int i = 0; i < 16; i++) {
    int dl = grp + i * 4;
    tile[dl][lane] = src[(size_t)(d0 + dl) * HW];  // coalesced along hw
  }
  __syncthreads();
  int dq = tid & 15;  // covers 4 d's
#pragma unroll
  for (int p = 0; p < 4; p++) {
    int n = (tid >> 4) + p * 16;  // hw_local
    int a0 = q0_of(tile[dq * 4 + 0][n]), b0 = q0_of(tile[dq * 4 + 1][n]);
    int c0 = q0_of(tile[dq * 4 + 2][n]), e0 = q0_of(tile[dq * 4 + 3][n]);
    int token = b * HW + hw0 + n;
    q0z[(size_t)token * (DIM / 4) + (d0 >> 2) + dq] = pack4(a0, b0, c0, e0);
  }
}

// ---- kernel 2: 2-pass GEMM + packed-u32 top-3 per code-eighth ----
// block = 256 threads (4 waves); wave = 32 tokens (2 tiles) x 32 codes/iter;
// 32 iters over one 1024-code eighth. A (q0z only) in registers.
// acc = 128*q0z.q0w + q0z.q1w ; score_int = iwsq2 - acc  (units 1/25600)
// pack = ((clamp(score)>>6)<<13) | idx13
// 2-pass z-side error: pairwise sigma ~0.65 abs; top-3/eighth + 6-sigma
// rescore threshold covers it (candidate-miss P ~ 2e-5/run).
// R5 lesson: VGPR cap (170 via (256,3)) must exceed live set (~130) or
// scratch spill (WRITE_SIZE explodes -> check counter).
__global__ __launch_bounds__(256, 3) void gemm_topk_kernel(
    const signed char* __restrict__ q0z, const signed char* __restrict__ q0w,
    const signed char* __restrict__ q1w, const int* __restrict__ iwsq2,
    uint4* __restrict__ partials) {
  // [buf][arr: 0=q0w k0-127, 1=q0w k128-255, 2=q1w k0-127, 3=q1w k128-255]
  // 32 rows x 128 B per array; slot t in row holds global chunk t^(row&7)
  // (R6-R9 proven zero-conflict geometry)
  __shared__ __align__(16) signed char sB[2][4][32 * 128];

  const int bid = blockIdx.x;   // 0..1023
  const int kq = bid & 7;       // code eighth, pinned per XCD
  const int tg = bid >> 3;      // 0..127 token group (128 tokens)
  const int tid = threadIdx.x;
  const int lane = tid & 63, w = tid >> 6;  // 4 waves x 32 tokens
  const int c = lane & 15, quad = lane >> 4;
  const int n0 = tg * 128;
  const int k0g = kq * 1024;

  // A fragments (coarse z only): global -> registers, once
  int4v af0[2][4];
#pragma unroll
  for (int t = 0; t < 2; t++) {
    const size_t arow = (size_t)(n0 + w * 32 + t * 16 + c) * DIM;
#pragma unroll
    for (int s = 0; s < 4; s++)
      af0[t][s] = *(const int4v*)(q0z + arow + s * 64 + quad * 16);
  }

  // staging: 256 chunks per array, thread tid stages chunk tid
  const int srow = tid >> 3;                      // 0..31
  const int scl = ((tid & 7) ^ (srow & 7)) * 16;  // source chunk (swizzled)
  const signed char* p0 = q0w + (size_t)(k0g + srow) * DIM + scl;
  const signed char* p1 = q1w + (size_t)(k0g + srow) * DIM + scl;
  async_cp16(&sB[0][0][tid * 16], p0);
  async_cp16(&sB[0][1][tid * 16], p0 + 128);
  async_cp16(&sB[0][2][tid * 16], p1);
  async_cp16(&sB[0][3][tid * 16], p1 + 128);
  p0 += 32 * DIM;
  p1 += 32 * DIM;
  __syncthreads();

  unsigned int m1[8], m2[8], m3[8];
#pragma unroll
  for (int i = 0; i < 8; i++) {
    m1[i] = 0xFFFFFFFFu; m2[i] = 0xFFFFFFFFu; m3[i] = 0xFFFFFFFFu;
  }

  unsigned int idxA = (unsigned)(k0g + c);
  const int4v zero = {0, 0, 0, 0};

  for (int it = 0; it < 32; it++) {
    const int buf = it & 1;
    if (it + 1 < 32) {  // stage next 32-code tile into other buffer
      const int nb = buf ^ 1;
      async_cp16(&sB[nb][0][tid * 16], p0);
      async_cp16(&sB[nb][1][tid * 16], p0 + 128);
      async_cp16(&sB[nb][2][tid * 16], p1);
      async_cp16(&sB[nb][3][tid * 16], p1 + 128);
      p0 += 32 * DIM;
      p1 += 32 * DIM;
    }
    const int iw0 = iwsq2[k0g + it * 32 + c];       // L1-hot
    const int iw1 = iwsq2[k0g + it * 32 + 16 + c];

    // B q0 fragments for both cols (rows c and 16+c; (16+c)&7 == c&7)
    int4v b0a[4], b0b[4];
#pragma unroll
    for (int s = 0; s < 4; s++) {
      const int ph = ((((s & 1) << 2) + quad) ^ (c & 7)) * 16;
      b0a[s] = *(const int4v*)(&sB[buf][s >> 1][c * 128 + ph]);
      b0b[s] = *(const int4v*)(&sB[buf][s >> 1][(16 + c) * 128 + ph]);
    }
    int4v a[2][2];
    // P00
#pragma unroll
    for (int t = 0; t < 2; t++) {
      a[t][0] = __builtin_amdgcn_mfma_i32_16x16x64_i8(af0[t][0], b0a[0], zero, 0, 0, 0);
      a[t][1] = __builtin_amdgcn_mfma_i32_16x16x64_i8(af0[t][0], b0b[0], zero, 0, 0, 0);
#pragma unroll
      for (int s = 1; s < 4; s++) {
        a[t][0] = __builtin_amdgcn_mfma_i32_16x16x64_i8(af0[t][s], b0a[s], a[t][0], 0, 0, 0);
        a[t][1] = __builtin_amdgcn_mfma_i32_16x16x64_i8(af0[t][s], b0b[s], a[t][1], 0, 0, 0);
      }
    }
#pragma unroll
    for (int t = 0; t < 2; t++)
#pragma unroll
      for (int cn = 0; cn < 2; cn++)
#pragma unroll
        for (int r = 0; r < 4; r++) a[t][cn][r] <<= 7;  // 128*P00
    // P01 (af0 x q1w; b1 loaded late -> low pressure)
#pragma unroll
    for (int s = 0; s < 4; s++) {
      const int ph = ((((s & 1) << 2) + quad) ^ (c & 7)) * 16;
      int4v b1a = *(const int4v*)(&sB[buf][2 + (s >> 1)][c * 128 + ph]);
      int4v b1b = *(const int4v*)(&sB[buf][2 + (s >> 1)][(16 + c) * 128 + ph]);
#pragma unroll
      for (int t = 0; t < 2; t++) {
        a[t][0] = __builtin_amdgcn_mfma_i32_16x16x64_i8(af0[t][s], b1a, a[t][0], 0, 0, 0);
        a[t][1] = __builtin_amdgcn_mfma_i32_16x16x64_i8(af0[t][s], b1b, a[t][1], 0, 0, 0);
      }
    }
    // epilogue (C/D: col=lane&15, row=quad*4+r); col-pair min then top-3
    // (pair-min can only hide a code whose PAIR PARTNER beats it in approx —
    //  partner is an effectively random code, P~0)
#pragma unroll
    for (int t = 0; t < 2; t++) {
#pragma unroll
      for (int r = 0; r < 4; r++) {
        unsigned int s0 = (unsigned int)(iw0 - a[t][0][r]);
        unsigned int s1 = (unsigned int)(iw1 - a[t][1][r]);
        s0 = s0 < 0x2000000u ? s0 : 0x1FFFFFFu;
        s1 = s1 < 0x2000000u ? s1 : 0x1FFFFFFu;
        unsigned int pk0 = ((s0 << 7) & 0xFFFFE000u) | idxA;
        unsigned int pk1 = ((s1 << 7) & 0xFFFFE000u) | (idxA + 16);
        top3_insert(pk0 < pk1 ? pk0 : pk1, m1[t * 4 + r], m2[t * 4 + r],
                    m3[t * 4 + r]);
      }
    }
    idxA += 32;
    __syncthreads();  // drains next-tile staging (in flight all compute phase)
  }

  // merge top-3 across the 16 c-lanes (idx rides in low bits)
#pragma unroll
  for (int ix = 0; ix < 8; ix++) {
    unsigned int a1 = m1[ix], a2 = m2[ix], a3 = m3[ix];
#pragma unroll
    for (int off = 1; off < 16; off <<= 1) {
      unsigned int o1 = __shfl_xor(a1, off, 16);
      unsigned int o2 = __shfl_xor(a2, off, 16);
      unsigned int o3 = __shfl_xor(a3, off, 16);
      top3_insert(o1, a1, a2, a3);
      top3_insert(o2, a1, a2, a3);
      top3_insert(o3, a1, a2, a3);
    }
    m1[ix] = a1; m2[ix] = a2; m3[ix] = a3;
  }
  if (c == 0) {
#pragma unroll
    for (int t = 0; t < 2; t++) {
#pragma unroll
      for (int r = 0; r < 4; r++) {
        int token = n0 + w * 32 + t * 16 + quad * 4 + r;
        partials[(size_t)kq * NTOK + token] =
            make_uint4(m1[t * 4 + r], m2[t * 4 + r], m3[t * 4 + r], 0xFFFFFFFFu);
      }
    }
  }
}

// ---- kernel 3: parallel filter/rescore + gather/transpose ----
// 24 candidates (top-3 x 8 eighths). Survivor = within 1536 packed units
// (~6 sigma of 2-pass approx error) of min. 1 survivor: zero loads.
// Else fp64 rescore via LDS worklist (full waves, ~25% of tokens).
__global__ __launch_bounds__(256) void rescore_gather_kernel(
    const uint4* __restrict__ partials, const float* __restrict__ z,
    const float* __restrict__ emb, float* __restrict__ out) {
  __shared__ float tile[32][257];
  __shared__ int sid[32];
  __shared__ int wl[32];
  __shared__ int nwl;
  const int b = blockIdx.x >> 5;
  const int hw0 = (blockIdx.x & 31) * 32;
  const int tid = threadIdx.x;
  if (tid == 0) nwl = 0;
  __syncthreads();
  {
    const int tl = tid >> 3, sub = tid & 7;  // 32 tokens x 8 threads
    const int token = b * HW + hw0 + tl;
    uint4 e = partials[(size_t)sub * NTOK + token];
    unsigned int m = e.x < e.y ? e.x : e.y;
    m = e.z < m ? e.z : m;
#pragma unroll
    for (int off = 1; off < 8; off <<= 1) {
      unsigned int o = __shfl_xor(m, off, 8);
      m = o < m ? o : m;
    }
    const unsigned int thr = (m >> 13) + 1536;
    int cnt = (((e.x >> 13) <= thr) ? 1 : 0) + (((e.y >> 13) <= thr) ? 1 : 0) +
              (((e.z >> 13) <= thr) ? 1 : 0);
#pragma unroll
    for (int off = 1; off < 8; off <<= 1) cnt += __shfl_xor(cnt, off, 8);
    if (sub == 0) {
      if (cnt == 1) {
        sid[tl] = (int)(m & 0x1FFFu);
      } else {
        int i = atomicAdd(&nwl, 1);
        wl[i] = tl;
      }
    }
  }
  __syncthreads();
  // fallback: one wave per worklist entry, exact fp64 over survivors
  {
    const int w = tid >> 6, lane = tid & 63;
    for (int i = w; i < nwl; i += 4) {
      const int tl = wl[i];
      const int token = b * HW + hw0 + tl;
      unsigned int p[24];
#pragma unroll
      for (int q = 0; q < 8; q++) {
        uint4 t = partials[(size_t)q * NTOK + token];
        p[q * 3] = t.x;
        p[q * 3 + 1] = t.y;
        p[q * 3 + 2] = t.z;
      }
      unsigned int smin = p[0];
#pragma unroll
      for (int q = 1; q < 24; q++) smin = p[q] < smin ? p[q] : smin;
      const unsigned int thr = (smin >> 13) + 1536;
      float zv[4];
#pragma unroll
      for (int j = 0; j < 4; j++)
        zv[j] = z[(size_t)b * DIM * HW + (size_t)(lane * 4 + j) * HW + hw0 + tl];
      double best = 1e300;
      int bid2 = NEMB;
#pragma unroll
      for (int q = 0; q < 24; q++) {
        if ((p[q] >> 13) <= thr) {  // wave-uniform
          int id = (int)(p[q] & 0x1FFFu);
          const float4 wv = *(const float4*)(emb + (size_t)id * DIM + lane * 4);
          double s = (double)wv.x * ((double)wv.x - 2.0 * (double)zv[0]) +
                     (double)wv.y * ((double)wv.y - 2.0 * (double)zv[1]) +
                     (double)wv.z * ((double)wv.z - 2.0 * (double)zv[2]) +
                     (double)wv.w * ((double)wv.w - 2.0 * (double)zv[3]);
#pragma unroll
          for (int off = 32; off > 0; off >>= 1) s += __shfl_xor(s, off, 64);
          if (s < best || (s == best && id < bid2)) {
            best = s;
            bid2 = id;
          }
        }
      }
      if (lane == 0) sid[tl] = bid2;
    }
  }
  __syncthreads();
  // gather + transpose (R7-R9 proven)
  for (int i = 0; i < 32; i++)
    tile[i][tid] = emb[(size_t)sid[i] * DIM + tid];  // coalesced 1KB row loads
  __syncthreads();
  int h = tid & 31, dg = tid >> 5;
  for (int i = 0; i < 32; i++) {
    int d = i * 8 + dg;
    out[(size_t)b * DIM * HW + (size_t)d * HW + hw0 + h] = tile[h][d];
  }
}

extern "C" void kernel_launch(void* const* d_in, const int* in_sizes, int n_in,
                              void* d_out, int out_size, void* d_ws, size_t ws_size,
                              hipStream_t stream) {
  const float* z = (const float*)d_in[0];    // [16,256,32,32]
  const float* emb = (const float*)d_in[1];  // [8192,256]
  float* out = (float*)d_out;
  char* ws = (char*)d_ws;

  // ws: q0w 2M | q1w 2M | q0z 4M | iwsq2 32K | partials 2M
  signed char* q0w = (signed char*)(ws);
  signed char* q1w = (signed char*)(ws + 2097152);
  signed char* q0z = (signed char*)(ws + 4194304);
  int* iwsq2 = (int*)(ws + 8388608);
  uint4* partials = (uint4*)(ws + 8421376);

  prep_kernel<<<dim3(3072), 256, 0, stream>>>(
      emb, (unsigned int*)q0w, (unsigned int*)q1w, iwsq2, z, (unsigned int*)q0z);
  gemm_topk_kernel<<<dim3(1024), 256, 0, stream>>>(q0z, q0w, q1w, iwsq2,
                                                   partials);
  rescore_gather_kernel<<<dim3(512), 256, 0, stream>>>(partials, z, emb, out);
}